// Round 16
// baseline (465.527 us; speedup 1.0000x reference)
//
#include <hip/hip_runtime.h>
#include <math.h>

// ---------------- problem constants ----------------
constexpr int CB  = 2;
constexpr int CL  = 28 * 28 * 28;   // 21952
constexpr int CC  = 192;
constexpr int CM  = CB * CL;        // 43904 total tokens (= 128 windows * 343)

typedef unsigned short ushortT;
typedef __attribute__((ext_vector_type(8))) short bf16x8;
typedef __attribute__((ext_vector_type(4))) float f32x4;

// bijective XCD swizzle (m204)
__device__ __forceinline__ int xcd_swz(int lid, int total) {
  int q = total >> 3, r = total & 7;
  int x = lid & 7, s = lid >> 3;
  return (x < r ? x * (q + 1) : r * (q + 1) + (x - r) * q) + s;
}

__device__ __forceinline__ int tt_to_pos(int tt, int& b) {
  int bw = tt / 343;
  int n  = tt - bw * 343;
  b = bw >> 6;
  int wi = bw & 63;
  int n0 = n / 49, r = n - n0 * 49;
  int n1 = r / 7,  n2 = r - n1 * 7;
  int h = (wi >> 4) * 7 + n0;
  int w = ((wi >> 2) & 3) * 7 + n1;
  int t = (wi & 3) * 7 + n2;
  return (h * 28 + w) * 28 + t;
}

__device__ __forceinline__ float gelu_exact(float x) {
  return 0.5f * x * (1.0f + erff(x * 0.70710678118654752f));
}

__device__ __forceinline__ ushortT f2b(float x) {
  unsigned int u = __builtin_bit_cast(unsigned int, x);
  unsigned int r = (u + 0x7FFFu + ((u >> 16) & 1u)) >> 16;
  return (ushortT)r;
}
__device__ __forceinline__ float b2f(ushortT u) {
  return __builtin_bit_cast(float, (unsigned int)u << 16);
}

// async global->LDS, 16B per lane
typedef __attribute__((address_space(3))) unsigned int lds_uint;
typedef const __attribute__((address_space(1))) unsigned int glb_uint;
__device__ __forceinline__ void stage16(const ushortT* g, ushortT* l) {
#if defined(__has_builtin) && __has_builtin(__builtin_amdgcn_global_load_lds)
  __builtin_amdgcn_global_load_lds((glb_uint*)g, (lds_uint*)l, 16, 0, 0);
#else
  *(uint4*)l = *(const uint4*)g;
#endif
}

// swizzled LDS fragment pointer: 128B rows, 16B chunks, chunk ^= row&7
__device__ __forceinline__ const bf16x8* ldsfrag(const ushortT* base, int row, int chunk) {
  return (const bf16x8*)((const char*)base + row * 128 + ((chunk ^ (row & 7)) << 4));
}

// ---------------- fused: LayerNorm1 (x,y) + weight prep + rpb4 table ----------------
__global__ __launch_bounds__(256) void ln_prep_kernel(
    const float* __restrict__ in0, const float* __restrict__ in1,
    const float* __restrict__ g, const float* __restrict__ bb,
    ushortT* __restrict__ out0, ushortT* __restrict__ out1,
    const float* __restrict__ qkvw, const float* __restrict__ projw,
    const float* __restrict__ fc1w, const float* __restrict__ fc2w,
    const float* __restrict__ w1, const float* __restrict__ w2,
    const float* __restrict__ rpb,
    ushortT* qkvwb, ushortT* projwb, ushortT* fc1wb, ushortT* fc2wb,
    ushortT* w1rb, ushortT* w2rb, float4* rpb4) {
  int bid = blockIdx.x;
  if (bid < 21952) {
    int wave = threadIdx.x >> 6;
    int lane = threadIdx.x & 63;
    const float* in = (bid & 1) ? in1 : in0;
    ushortT* out = (bid & 1) ? out1 : out0;
    int row = (bid >> 1) * 4 + wave;
    const float* p = in + (size_t)row * CC;
    float v0 = p[lane], v1 = p[lane + 64], v2 = p[lane + 128];
    float s = v0 + v1 + v2;
    for (int o = 32; o; o >>= 1) s += __shfl_xor(s, o, 64);
    float mean = s * (1.0f / 192.0f);
    float d0 = v0 - mean, d1 = v1 - mean, d2 = v2 - mean;
    float qs = d0 * d0 + d1 * d1 + d2 * d2;
    for (int o = 32; o; o >>= 1) qs += __shfl_xor(qs, o, 64);
    float rs = rsqrtf(qs * (1.0f / 192.0f) + 1e-5f);
    ushortT* po = out + (size_t)row * CC;
    po[lane]       = f2b(d0 * rs * g[lane]       + bb[lane]);
    po[lane + 64]  = f2b(d1 * rs * g[lane + 64]  + bb[lane + 64]);
    po[lane + 128] = f2b(d2 * rs * g[lane + 128] + bb[lane + 128]);
    return;
  }
  int i = (bid - 21952) * 256 + threadIdx.x;
  if (i < 110592) { qkvwb[i] = f2b(qkvw[i]); return; }
  i -= 110592;
  if (i < 36864) { projwb[i] = f2b(projw[i]); return; }
  i -= 36864;
  if (i < 147456) { fc1wb[i] = f2b(fc1w[i]); return; }
  i -= 147456;
  if (i < 147456) { fc2wb[i] = f2b(fc2w[i]); return; }
  i -= 147456;
  if (i < 331776) {
    int o = i / 5184, r = i - o * 5184, tap = r / 192, c = r - tap * 192;
    w1rb[i] = f2b(w1[o * 5184 + c * 27 + tap]); return;
  }
  i -= 331776;
  if (i < 331776) {
    int o = i / 1728, r = i - o * 1728, tap = r / 64, c = r - tap * 64;
    w2rb[i] = f2b(w2[o * 1728 + c * 27 + tap]); return;
  }
  i -= 331776;
  if (i < 6 * 88 * 352) {
    int head = i / (88 * 352);
    int rem = i - head * 88 * 352;
    int qgrp = rem / 352, k = rem - qgrp * 352;
    float4 v = make_float4(0.f, 0.f, 0.f, 0.f);
    if (k < 343) {
      int b0 = k / 49, rb = k - b0 * 49; int b1 = rb / 7, b2 = rb - b1 * 7;
#pragma unroll
      for (int r = 0; r < 4; ++r) {
        int q = qgrp * 4 + r;
        if (q < 343) {
          int a0 = q / 49, ra = q - a0 * 49; int a1 = ra / 7, a2 = ra - a1 * 7;
          int ridx = ((a0 - b0 + 6) * 13 + (a1 - b1 + 6)) * 13 + (a2 - b2 + 6);
          (&v.x)[r] = rpb[ridx * 6 + head];
        }
      }
    }
    rpb4[i] = v;
  }
}

// ======== shared core macros (BM=64 core; BX passed explicitly) ========
#define CORE_IDS \
  const int tid = threadIdx.x; \
  const int wave = tid >> 6, lane = tid & 63; \
  const int fr = lane & 15, g = lane >> 4; \
  const int wr = wave >> 1, wc = wave & 1;

#define ZERO_ACC(NF) \
  f32x4 acc[2][NF]; \
  _Pragma("unroll") \
  for (int m_ = 0; m_ < 2; ++m_) { \
    _Pragma("unroll") \
    for (int n_ = 0; n_ < NF; ++n_) acc[m_][n_] = (f32x4){0.f, 0.f, 0.f, 0.f}; \
  }

#define SETUP_A_ROWMAJOR(BASE, LDA, BX) \
  const ushortT* pa[2]; ushortT* la[2]; \
  _Pragma("unroll") \
  for (int i = 0; i < 2; ++i) { \
    int slot = i * 256 + tid; int row_ = slot >> 3; \
    int cc8 = ((slot & 7) ^ (row_ & 7)) * 8; \
    pa[i] = (BASE) + (size_t)((BX) * 64 + row_) * (LDA) + cc8; \
    la[i] = Asl + slot * 8; \
  }

#define SETUP_A_WINDOWED(BASE, BX) \
  const ushortT* pa[2]; ushortT* la[2]; \
  _Pragma("unroll") \
  for (int i = 0; i < 2; ++i) { \
    int slot = i * 256 + tid; int row_ = slot >> 3; \
    int cc8 = ((slot & 7) ^ (row_ & 7)) * 8; \
    int bq_; int pos_ = tt_to_pos((BX) * 64 + row_, bq_); \
    pa[i] = (BASE) + ((size_t)bq_ * CL + pos_) * CC + cc8; \
    la[i] = Asl + slot * 8; \
  }

#define SETUP_B(BASE, ROWOFF, LDB, NR) \
  const ushortT* pb[NR]; ushortT* lb[NR]; \
  _Pragma("unroll") \
  for (int i = 0; i < NR; ++i) { \
    int slot = i * 256 + tid; int row_ = slot >> 3; \
    int cc8 = ((slot & 7) ^ (row_ & 7)) * 8; \
    pb[i] = (BASE) + (size_t)((ROWOFF) + row_) * (LDB) + cc8; \
    lb[i] = Bsl + slot * 8; \
  }

#define STAGE_AB(NR) \
  _Pragma("unroll") \
  for (int i = 0; i < 2; ++i) { stage16(pa[i], la[i]); pa[i] += 64; } \
  _Pragma("unroll") \
  for (int i = 0; i < NR; ++i) { stage16(pb[i], lb[i]); pb[i] += 64; }

#define CORE_MFMA(NF) \
  __syncthreads(); \
  _Pragma("unroll") \
  for (int kk = 0; kk < 2; ++kk) { \
    bf16x8 a0 = *ldsfrag(Asl, wr * 32 + fr, kk * 4 + g); \
    bf16x8 a1 = *ldsfrag(Asl, wr * 32 + 16 + fr, kk * 4 + g); \
    _Pragma("unroll") \
    for (int n_ = 0; n_ < NF; ++n_) { \
      bf16x8 bn = *ldsfrag(Bsl, wc * ((NF) * 16) + n_ * 16 + fr, kk * 4 + g); \
      acc[0][n_] = __builtin_amdgcn_mfma_f32_16x16x32_bf16(a0, bn, acc[0][n_], 0, 0, 0); \
      acc[1][n_] = __builtin_amdgcn_mfma_f32_16x16x32_bf16(a1, bn, acc[1][n_], 0, 0, 0); \
    } \
  } \
  __syncthreads();

// ======== 128x128 core (uses local `mblk`) ========
#define M128_ZERO \
  f32x4 acc[4][4]; \
  _Pragma("unroll") \
  for (int m_ = 0; m_ < 4; ++m_) \
    _Pragma("unroll") \
    for (int n_ = 0; n_ < 4; ++n_) acc[m_][n_] = (f32x4){0.f, 0.f, 0.f, 0.f};

#define M128_SETUP_A_ROWMAJOR(BASE, LDA) \
  const ushortT* pa[4]; ushortT* la[4]; \
  _Pragma("unroll") \
  for (int i = 0; i < 4; ++i) { \
    int slot = i * 256 + tid; int row_ = slot >> 3; \
    int cc8 = ((slot & 7) ^ (row_ & 7)) * 8; \
    pa[i] = (BASE) + (size_t)(mblk * 128 + row_) * (LDA) + cc8; \
    la[i] = Asl + slot * 8; \
  }

#define M128_SETUP_A_WINDOWED(BASE) \
  const ushortT* pa[4]; ushortT* la[4]; \
  _Pragma("unroll") \
  for (int i = 0; i < 4; ++i) { \
    int slot = i * 256 + tid; int row_ = slot >> 3; \
    int cc8 = ((slot & 7) ^ (row_ & 7)) * 8; \
    int bq_; int pos_ = tt_to_pos(mblk * 128 + row_, bq_); \
    pa[i] = (BASE) + ((size_t)bq_ * CL + pos_) * CC + cc8; \
    la[i] = Asl + slot * 8; \
  }

#define M128_SETUP_B(BASE, ROWOFF, LDB) \
  const ushortT* pb[4]; ushortT* lb[4]; \
  _Pragma("unroll") \
  for (int i = 0; i < 4; ++i) { \
    int slot = i * 256 + tid; int row_ = slot >> 3; \
    int cc8 = ((slot & 7) ^ (row_ & 7)) * 8; \
    pb[i] = (BASE) + (size_t)((ROWOFF) + row_) * (LDB) + cc8; \
    lb[i] = Bsl + slot * 8; \
  }

#define M128_STAGE \
  { _Pragma("unroll") \
    for (int i = 0; i < 4; ++i) { stage16(pa[i], la[i]); pa[i] += 64; } \
    _Pragma("unroll") \
    for (int i = 0; i < 4; ++i) { stage16(pb[i], lb[i]); pb[i] += 64; } }

#define M128_MFMA \
  { _Pragma("unroll") \
    for (int kk = 0; kk < 2; ++kk) { \
      bf16x8 am[4], bn[4]; \
      _Pragma("unroll") \
      for (int m_ = 0; m_ < 4; ++m_) am[m_] = *ldsfrag(Asl, wr * 64 + m_ * 16 + fr, kk * 4 + g); \
      _Pragma("unroll") \
      for (int n_ = 0; n_ < 4; ++n_) bn[n_] = *ldsfrag(Bsl, wc * 64 + n_ * 16 + fr, kk * 4 + g); \
      _Pragma("unroll") \
      for (int m_ = 0; m_ < 4; ++m_) \
        _Pragma("unroll") \
        for (int n_ = 0; n_ < 4; ++n_) \
          acc[m_][n_] = __builtin_amdgcn_mfma_f32_16x16x32_bf16(am[m_], bn[n_], acc[m_][n_], 0, 0, 0); \
    } }

#define M128_LOOP(KS) \
  _Pragma("unroll") \
  for (int ks = 0; ks < (KS); ++ks) { \
    M128_STAGE \
    __syncthreads(); \
    M128_MFMA \
    __syncthreads(); \
  }

// ---------------- device bodies ----------------
__device__ __forceinline__ void gemmq_body(int bx, ushortT* Asl, ushortT* Bsl,
                                           const ushortT* __restrict__ xnb,
                                           const ushortT* __restrict__ qkvwb,
                                           const float* __restrict__ qkvb,
                                           ushortT* __restrict__ qout) {
  CORE_IDS
  ZERO_ACC(6)
  SETUP_A_WINDOWED(xnb, bx)
  SETUP_B(qkvwb, 0, 192, 6)
  for (int ks = 0; ks < 3; ++ks) {
    STAGE_AB(6)
    CORE_MFMA(6)
  }
#pragma unroll
  for (int n = 0; n < 6; ++n) {
    int jj = wc * 96 + n * 16 + fr;
    int head = jj >> 5, d = jj & 31;
    float bias = qkvb[jj];
#pragma unroll
    for (int m = 0; m < 2; ++m)
#pragma unroll
      for (int r = 0; r < 4; ++r) {
        int tt = bx * 64 + wr * 32 + m * 16 + g * 4 + r;
        int bw = tt / 343, nn = tt - bw * 343;
        qout[(((size_t)bw * 6 + head) * 343 + nn) * 32 + d] =
            f2b((acc[m][n][r] + bias) * 0.17677669529663687f);
      }
  }
}

__device__ __forceinline__ void kv_body(int bx, ushortT* Asl, ushortT* Bsl,
                                        const ushortT* __restrict__ ynb,
                                        const ushortT* __restrict__ qkvwb,
                                        const float* __restrict__ qkvb,
                                        ushortT* __restrict__ kout,
                                        ushortT* __restrict__ vout) {
  CORE_IDS
  const int wid = xcd_swz(bx, 343 * 3);
  const int mblk = wid / 3;
  const int jb = (wid - mblk * 3) * 128;
  M128_ZERO
  M128_SETUP_A_WINDOWED(ynb)
  M128_SETUP_B(qkvwb, 192 + jb, 192)
  M128_LOOP(3)
#pragma unroll
  for (int ni = 0; ni < 4; ++ni) {
    int jj = jb + wc * 64 + ni * 16 + fr;
    float bias = qkvb[192 + jj];
#pragma unroll
    for (int mi = 0; mi < 4; ++mi)
#pragma unroll
      for (int r = 0; r < 4; ++r) {
        int tt = mblk * 128 + wr * 64 + mi * 16 + g * 4 + r;
        int bw = tt / 343, nn = tt - bw * 343;
        float val = acc[mi][ni][r] + bias;
        if (jj < 192) {
          int head = jj >> 5, d = jj & 31;
          kout[(((size_t)bw * 6 + head) * 343 + nn) * 32 + d] = f2b(val);
        } else {
          int jv = jj - 192;
          int head = jv >> 5, d = jv & 31;
          vout[((size_t)bw * 6 + head) * 11264 + (size_t)d * 352 + nn] = f2b(val);
        }
      }
  }
}

// conv body: MODE 2 = split-K fp32 partial (conv1), MODE 0 = bf16+bias+pool (conv2)
template <int CIN, int COUTT, int MODE>
__device__ __forceinline__ void conv_body(int bx, ushortT* Asl, ushortT* Bsl,
                                          const ushortT* __restrict__ src,
                                          const ushortT* __restrict__ wrw,
                                          const float* __restrict__ bias,
                                          void* __restrict__ dst,
                                          float* __restrict__ part) {
  constexpr int KT = 27 * CIN;
  constexpr int KN = KT / 64;
  constexpr int NY = (MODE == 2) ? 4 : (COUTT / 64);
  constexpr int NBLK = 343 * NY;
  const int tid = threadIdx.x;
  const int wave = tid >> 6, lane = tid & 63;
  const int fr = lane & 15, g = lane >> 4;
  const int wid = xcd_swz(bx, NBLK);
  const int mblk = wid / NY;
  const int ysub = wid - mblk * NY;
  f32x4 acc[2][4];
#pragma unroll
  for (int m = 0; m < 2; ++m)
#pragma unroll
    for (int n = 0; n < 4; ++n) acc[m][n] = (f32x4){0.f, 0.f, 0.f, 0.f};

  const int kb = (MODE == 2) ? (ysub * KN) / 4 : 0;
  const int ke = (MODE == 2) ? ((ysub + 1) * KN) / 4 : KN;
  const int jbN = (MODE == 0) ? ysub * 64 : 0;

  const ushortT* srcb[4];
  ushortT* la[4];
  unsigned vmask[4];
#pragma unroll
  for (int i = 0; i < 4; ++i) {
    int slot = i * 256 + tid; int row_ = slot >> 3;
    int cc8 = ((slot & 7) ^ (row_ & 7)) * 8;
    int grow = mblk * 128 + row_;
    int bbq = grow / CL;
    int pos = grow - bbq * CL;
    int h = pos / 784, w = (pos / 28) % 28, t = pos % 28;
    unsigned vm = 0;
#pragma unroll
    for (int tap = 0; tap < 27; ++tap) {
      int dh = tap / 9 - 1, dw = (tap / 3) % 3 - 1, dt = tap % 3 - 1;
      bool ok = ((unsigned)(h + dh) < 28u) && ((unsigned)(w + dw) < 28u) &&
                ((unsigned)(t + dt) < 28u);
      vm |= (unsigned)ok << tap;
    }
    vmask[i] = vm;
    srcb[i] = src + ((size_t)bbq * CL + pos) * CIN + cc8;
    la[i] = Asl + slot * 8;
  }
  const ushortT* pb[2]; ushortT* lb[2];
#pragma unroll
  for (int i = 0; i < 2; ++i) {
    int slot = i * 256 + tid; int row_ = slot >> 3;
    int cc8 = ((slot & 7) ^ (row_ & 7)) * 8;
    pb[i] = wrw + (size_t)(jbN + row_) * KT + kb * 64 + cc8;
    lb[i] = Bsl + slot * 8;
  }

  auto loadA = [&](int ks, int i) -> uint4 {
    int tap, cb;
    if (CIN == 64) { tap = ks; cb = 0; }
    else           { tap = ks / 3; cb = (ks - tap * 3) * 64; }
    int off = ((tap / 9 - 1) * 784 + ((tap / 3) % 3 - 1) * 28 + (tap % 3 - 1)) * CIN + cb;
    uint4 v = make_uint4(0u, 0u, 0u, 0u);
    if ((vmask[i] >> tap) & 1u) v = *(const uint4*)(srcb[i] + off);
    return v;
  };

  uint4 vr[4];
#pragma unroll
  for (int i = 0; i < 4; ++i) vr[i] = loadA(kb, i);
  for (int ks = kb; ks < ke; ++ks) {
#pragma unroll
    for (int i = 0; i < 4; ++i) *(uint4*)la[i] = vr[i];
#pragma unroll
    for (int i = 0; i < 2; ++i) { stage16(pb[i], lb[i]); pb[i] += 64; }
    __syncthreads();
    bool more = (ks + 1 < ke);
    if (more) {
#pragma unroll
      for (int i = 0; i < 4; ++i) vr[i] = loadA(ks + 1, i);
    }
#pragma unroll
    for (int kk = 0; kk < 2; ++kk) {
      bf16x8 a0 = *ldsfrag(Asl, wave * 32 + fr, kk * 4 + g);
      bf16x8 a1 = *ldsfrag(Asl, wave * 32 + 16 + fr, kk * 4 + g);
#pragma unroll
      for (int n = 0; n < 4; ++n) {
        bf16x8 bn = *ldsfrag(Bsl, n * 16 + fr, kk * 4 + g);
        acc[0][n] = __builtin_amdgcn_mfma_f32_16x16x32_bf16(a0, bn, acc[0][n], 0, 0, 0);
        acc[1][n] = __builtin_amdgcn_mfma_f32_16x16x32_bf16(a1, bn, acc[1][n], 0, 0, 0);
      }
    }
    __syncthreads();
  }
  if (MODE == 2) {
#pragma unroll
    for (int n = 0; n < 4; ++n) {
      int jj = n * 16 + fr;
#pragma unroll
      for (int m = 0; m < 2; ++m)
#pragma unroll
        for (int r = 0; r < 4; ++r) {
          int grow = mblk * 128 + wave * 32 + m * 16 + g * 4 + r;
          ((float*)dst)[((size_t)ysub * CM + grow) * 64 + jj] = acc[m][n][r];
        }
    }
  } else {
    float* red = (float*)Asl;
#pragma unroll
    for (int n = 0; n < 4; ++n) {
      int jj = n * 16 + fr;
      float bs = bias[jbN + jj];
      float s0 = 0.f, s1 = 0.f;
#pragma unroll
      for (int m = 0; m < 2; ++m)
#pragma unroll
        for (int r = 0; r < 4; ++r) {
          int grow = mblk * 128 + wave * 32 + m * 16 + g * 4 + r;
          float v = acc[m][n][r] + bs;
          ((ushortT*)dst)[(size_t)grow * COUTT + jbN + jj] = f2b(v);
          if (grow < CL) s0 += v; else s1 += v;
        }
      s0 += __shfl_xor(s0, 16, 64); s0 += __shfl_xor(s0, 32, 64);
      s1 += __shfl_xor(s1, 16, 64); s1 += __shfl_xor(s1, 32, 64);
      if (g == 0) {
        red[((wave * 4 + n) * 16 + fr) * 2 + 0] = s0;
        red[((wave * 4 + n) * 16 + fr) * 2 + 1] = s1;
      }
    }
    __syncthreads();
    if (tid < 128) {
      int chl = tid >> 1, bsel = tid & 1;
      float s = 0.f;
#pragma unroll
      for (int wv = 0; wv < 4; ++wv)
        s += red[((wv * 4 + (chl >> 4)) * 16 + (chl & 15)) * 2 + bsel];
      if (s != 0.0f) atomicAdd(&part[bsel * 192 + jbN + chl], s);
    }
  }
}

// attn body (r12 form: no-max softmax, LDS-staged, no setprio)
constexpr int KP  = 36;
constexpr int VP  = 356;
constexpr int VP2 = 200;

__device__ __forceinline__ void attn_body(int bx, ushortT* Kl, ushortT* Vt, ushortT* Pl,
                                          const ushortT* __restrict__ qb,
                                          const ushortT* __restrict__ kb,
                                          const ushortT* __restrict__ vb,
                                          const float* __restrict__ rpb4,
                                          ushortT* __restrict__ aout) {
  const int tid = threadIdx.x;
  const int wave = tid >> 6, lane = tid & 63;
  const int fr = lane & 15, g = lane >> 4, fk = g * 8;
  const int wid = xcd_swz(bx, 768 * 2);
  const int wh = wid >> 1;
  const int qhalf = wid & 1;
  const int bw = wh / 6, head = wh - bw * 6;
  const ushortT* kp = kb + (size_t)wh * 343 * 32;
  const ushortT* vp = vb + (size_t)wh * 11264;
  const ushortT* qp = qb + (size_t)wh * 343 * 32;
  const f32x4* bp4 = (const f32x4*)rpb4 + (size_t)head * 88 * 352;

  for (int c = tid; c < 1372; c += 256) {
    int key = c >> 2, pp = c & 3;
    *(uint4*)&Kl[key * KP + pp * 8] = *(const uint4*)(kp + (size_t)c * 8);
  }
  for (int c = tid; c < 1408; c += 256) {
    int d = c / 44, p = c - d * 44;
    *(uint4*)&Vt[d * VP + p * 8] = *(const uint4*)(vp + (size_t)c * 8);
  }
  __syncthreads();

  for (int qi = 0; qi < 3; ++qi) {
    const int q0 = (qhalf * 3 + qi) * 64;

    int qrow = q0 + wave * 16 + fr; if (qrow > 342) qrow = 342;
    bf16x8 aq = *(const bf16x8*)(qp + (size_t)qrow * 32 + fk);

    const int qgrp = (q0 + wave * 16) / 4 + g;
    f32x4 sc[22];
#pragma unroll
    for (int t = 0; t < 22; ++t) {
      f32x4 cini = bp4[(size_t)qgrp * 352 + t * 16 + fr];
      bf16x8 bk = *(const bf16x8*)&Kl[(t * 16 + fr) * KP + fk];
      sc[t] = __builtin_amdgcn_mfma_f32_16x16x32_bf16(aq, bk, cini, 0, 0, 0);
    }
    if (fr > 6) { sc[21][0] = -1e30f; sc[21][1] = -1e30f; sc[21][2] = -1e30f; sc[21][3] = -1e30f; }

    float rinv[4];
#pragma unroll
    for (int r = 0; r < 4; ++r) {
      float sum = 0.0f;
#pragma unroll
      for (int t = 0; t < 22; ++t) {
        float e = __expf(sc[t][r]);
        sc[t][r] = e;
        sum += e;
      }
      sum += __shfl_xor(sum, 1, 64); sum += __shfl_xor(sum, 2, 64);
      sum += __shfl_xor(sum, 4, 64); sum += __shfl_xor(sum, 8, 64);
      rinv[r] = 1.0f / sum;
    }

    f32x4 o0 = {0.f, 0.f, 0.f, 0.f}, o1 = {0.f, 0.f, 0.f, 0.f};

#pragma unroll
    for (int t = 0; t < 12; ++t)
#pragma unroll
      for (int r = 0; r < 4; ++r)
        Pl[(wave * 16 + g * 4 + r) * VP2 + t * 16 + fr] = f2b(sc[t][r]);
    asm volatile("s_waitcnt lgkmcnt(0)" ::: "memory");
#pragma unroll
    for (int s = 0; s < 6; ++s) {
      bf16x8 ap  = *(const bf16x8*)&Pl[(wave * 16 + fr) * VP2 + s * 32 + fk];
      bf16x8 bv0 = *(const bf16x8*)&Vt[fr * VP + s * 32 + fk];
      bf16x8 bv1 = *(const bf16x8*)&Vt[(16 + fr) * VP + s * 32 + fk];
      o0 = __builtin_amdgcn_mfma_f32_16x16x32_bf16(ap, bv0, o0, 0, 0, 0);
      o1 = __builtin_amdgcn_mfma_f32_16x16x32_bf16(ap, bv1, o1, 0, 0, 0);
    }
    asm volatile("s_waitcnt lgkmcnt(0)" ::: "memory");

#pragma unroll
    for (int t = 12; t < 22; ++t)
#pragma unroll
      for (int r = 0; r < 4; ++r)
        Pl[(wave * 16 + g * 4 + r) * VP2 + (t - 12) * 16 + fr] = f2b(sc[t][r]);
    asm volatile("s_waitcnt lgkmcnt(0)" ::: "memory");
#pragma unroll
    for (int s = 0; s < 5; ++s) {
      bf16x8 ap  = *(const bf16x8*)&Pl[(wave * 16 + fr) * VP2 + s * 32 + fk];
      bf16x8 bv0 = *(const bf16x8*)&Vt[fr * VP + 192 + s * 32 + fk];
      bf16x8 bv1 = *(const bf16x8*)&Vt[(16 + fr) * VP + 192 + s * 32 + fk];
      o0 = __builtin_amdgcn_mfma_f32_16x16x32_bf16(ap, bv0, o0, 0, 0, 0);
      o1 = __builtin_amdgcn_mfma_f32_16x16x32_bf16(ap, bv1, o1, 0, 0, 0);
    }
    asm volatile("s_waitcnt lgkmcnt(0)" ::: "memory");

#pragma unroll
    for (int r = 0; r < 4; ++r) {
      int q = q0 + wave * 16 + g * 4 + r;
      if (q < 343) {
        float ri = rinv[r];
        size_t base = ((size_t)bw * 343 + q) * 192 + head * 32;
        aout[base + fr]      = f2b(o0[r] * ri);
        aout[base + 16 + fr] = f2b(o1[r] * ri);
      }
    }
  }
}

// ---------------- phase A: conv1 + kv + gemm_q (independent, one launch) ----------------
__global__ __launch_bounds__(256) void phaseA(const ushortT* __restrict__ xnb,
                                              const ushortT* __restrict__ ynb,
                                              const ushortT* __restrict__ qkvwb,
                                              const float* __restrict__ qkvb,
                                              const ushortT* __restrict__ w1rb,
                                              ushortT* __restrict__ qout,
                                              ushortT* __restrict__ kout,
                                              ushortT* __restrict__ vout,
                                              float* __restrict__ pc1) {
  __shared__ alignas(16) ushortT SH[16384];   // 32 KB
  const int bid = blockIdx.x;
  if (bid < 1372) {
    conv_body<192, 64, 2>(bid, SH, SH + 8192, xnb, w1rb, nullptr, pc1, nullptr);
  } else if (bid < 2401) {
    kv_body(bid - 1372, SH, SH + 8192, ynb, qkvwb, qkvb, kout, vout);
  } else {
    gemmq_body(bid - 2401, SH, SH + 4096, xnb, qkvwb, qkvb, qout);
  }
}

// ---------------- conv1 combine ----------------
__global__ __launch_bounds__(256) void comb1_kernel(const float* __restrict__ pc,
                                                    const float* __restrict__ b1,
                                                    ushortT* __restrict__ h1b) {
  size_t idx = ((size_t)blockIdx.x * 256 + threadIdx.x) * 4;
  float4 a = *(const float4*)(pc + idx);
  float4 b = *(const float4*)(pc + (size_t)CM * 64 + idx);
  float4 c = *(const float4*)(pc + (size_t)CM * 128 + idx);
  float4 d = *(const float4*)(pc + (size_t)CM * 192 + idx);
  int c0 = (int)(idx & 63);
  ushortT o0 = f2b(gelu_exact(a.x + b.x + c.x + d.x + b1[c0 + 0]));
  ushortT o1 = f2b(gelu_exact(a.y + b.y + c.y + d.y + b1[c0 + 1]));
  ushortT o2 = f2b(gelu_exact(a.z + b.z + c.z + d.z + b1[c0 + 2]));
  ushortT o3 = f2b(gelu_exact(a.w + b.w + c.w + d.w + b1[c0 + 3]));
  unsigned int w0 = (unsigned int)o0 | ((unsigned int)o1 << 16);
  unsigned int w1 = (unsigned int)o2 | ((unsigned int)o3 << 16);
  *(uint2*)&h1b[idx] = make_uint2(w0, w1);
}

// ---------------- conv2 || attention (independent, one launch) ----------------
__global__ __launch_bounds__(256) void conv2attn(const ushortT* __restrict__ h1b,
                                                 const ushortT* __restrict__ w2rb,
                                                 const float* __restrict__ b2,
                                                 ushortT* __restrict__ h2b,
                                                 float* __restrict__ part,
                                                 const ushortT* __restrict__ qb,
                                                 const ushortT* __restrict__ kb,
                                                 const ushortT* __restrict__ vb,
                                                 const float* __restrict__ rpb4,
                                                 ushortT* __restrict__ aout) {
  __shared__ alignas(16) ushortT SH[36864];   // 72 KB (attn layout)
  const int bid = blockIdx.x;
  if (bid < 1029) {
    conv_body<64, 192, 0>(bid, SH, SH + 8192, h1b, w2rb, b2, h2b, part);
  } else {
    attn_body(bid - 1029, SH, SH + 12672, SH + 24064, qb, kb, vb, rpb4, aout);
  }
}

// ---------------- channel attention (tiny) ----------------
__global__ __launch_bounds__(192) void ca_kernel(const float* __restrict__ part,
                                                 const float* __restrict__ ca1w,
                                                 const float* __restrict__ ca1b,
                                                 const float* __restrict__ ca2w,
                                                 const float* __restrict__ ca2b,
                                                 float* __restrict__ av) {
  __shared__ float pl[192];
  __shared__ float hid[12];
  int c = threadIdx.x, b = blockIdx.x;
  pl[c] = part[b * 192 + c] * (1.0f / (float)CL);
  __syncthreads();
  if (c < 12) {
    float t = ca1b[c];
    for (int i = 0; i < 192; ++i) t += ca1w[c * 192 + i] * pl[i];
    hid[c] = fmaxf(t, 0.0f);
  }
  __syncthreads();
  float t = ca2b[c];
#pragma unroll
  for (int j = 0; j < 12; ++j) t += ca2w[c * 12 + j] * hid[j];
  av[b * 192 + c] = 1.0f / (1.0f + __expf(-t));
}

// ---------------- proj + window-reverse + residual + FUSED LayerNorm2 ----------------
__global__ __launch_bounds__(256) void proj_ln(const ushortT* __restrict__ attnrb,
                                               const ushortT* __restrict__ projwb,
                                               const float* __restrict__ projb,
                                               const float* __restrict__ x0,
                                               const ushortT* __restrict__ h2b,
                                               const float* __restrict__ cav,
                                               const float* __restrict__ n2g,
                                               const float* __restrict__ n2b,
                                               float* __restrict__ xout,
                                               ushortT* __restrict__ hlnb) {
  __shared__ alignas(16) ushortT Asl[64 * 64];
  __shared__ alignas(16) ushortT Bsl[192 * 64];
  CORE_IDS
  const int bx = blockIdx.x;
  ZERO_ACC(6)
  SETUP_A_ROWMAJOR(attnrb, CC, bx)
  SETUP_B(projwb, 0, 192, 6)
  for (int ks = 0; ks < 3; ++ks) {
    STAGE_AB(6)
    CORE_MFMA(6)
  }
  size_t sbase[2][4];
#pragma unroll
  for (int m = 0; m < 2; ++m)
#pragma unroll
    for (int r = 0; r < 4; ++r) {
      int tt = bx * 64 + wr * 32 + m * 16 + g * 4 + r;
      int bq_;
      int pos_ = tt_to_pos(tt, bq_);
      size_t base = ((size_t)bq_ * CL + pos_) * CC;
      sbase[m][r] = base;
#pragma unroll
      for (int n = 0; n < 6; ++n) {
        int jj = wc * 96 + n * 16 + fr;
        size_t addr = base + jj;
        float v = x0[addr] + acc[m][n][r] + projb[jj] + b2f(h2b[addr]) * cav[bq_ * 192 + jj];
        acc[m][n][r] = v;
        xout[addr] = v;
      }
    }
  float* stats = (float*)Asl;
#pragma unroll
  for (int m = 0; m < 2; ++m)
#pragma unroll
    for (int r = 0; r < 4; ++r) {
      float ps = 0.f, ps2 = 0.f;
#pragma unroll
      for (int n = 0; n < 6; ++n) { float v = acc[m][n][r]; ps += v; ps2 += v * v; }
      ps  += __shfl_xor(ps, 1, 64);  ps2 += __shfl_xor(ps2, 1, 64);
      ps  += __shfl_xor(ps, 2, 64);  ps2 += __shfl_xor(ps2, 2, 64);
      ps  += __shfl_xor(ps, 4, 64);  ps2 += __shfl_xor(ps2, 4, 64);
      ps  += __shfl_xor(ps, 8, 64);  ps2 += __shfl_xor(ps2, 8, 64);
      if (fr == 0) {
        int lrow = wr * 32 + m * 16 + g * 4 + r;
        stats[lrow * 4 + wc * 2]     = ps;
        stats[lrow * 4 + wc * 2 + 1] = ps2;
      }
    }
  __syncthreads();
#pragma unroll
  for (int m = 0; m < 2; ++m)
#pragma unroll
    for (int r = 0; r < 4; ++r) {
      int lrow = wr * 32 + m * 16 + g * 4 + r;
      float s  = stats[lrow * 4]     + stats[lrow * 4 + 2];
      float s2 = stats[lrow * 4 + 1] + stats[lrow * 4 + 3];
      float mean = s * (1.0f / 192.0f);
      float var  = s2 * (1.0f / 192.0f) - mean * mean;
      float rs = rsqrtf(var + 1e-5f);
      ushortT* po = hlnb + sbase[m][r];
#pragma unroll
      for (int n = 0; n < 6; ++n) {
        int jj = wc * 96 + n * 16 + fr;
        po[jj] = f2b((acc[m][n][r] - mean) * rs * n2g[jj] + n2b[jj]);
      }
    }
}

// ---------------- MLP fc1 (128x128 core, XCD-swizzled) ----------------
__global__ __launch_bounds__(256) void fc1_128(const ushortT* __restrict__ hlnb,
                                               const ushortT* __restrict__ fc1wb,
                                               const float* __restrict__ fc1b,
                                               ushortT* __restrict__ hidb) {
  __shared__ alignas(16) ushortT Asl[8192];
  __shared__ alignas(16) ushortT Bsl[8192];
  CORE_IDS
  const int wid = xcd_swz(blockIdx.x, 343 * 6);
  const int mblk = wid / 6;
  const int jb = (wid - mblk * 6) * 128;
  M128_ZERO
  M128_SETUP_A_ROWMAJOR(hlnb, CC)
  M128_SETUP_B(fc1wb, jb, 192)
  M128_LOOP(3)
#pragma unroll
  for (int ni = 0; ni < 4; ++ni) {
    int jj = jb + wc * 64 + ni * 16 + fr;
    float bs = fc1b[jj];
#pragma unroll
    for (int mi = 0; mi < 4; ++mi)
#pragma unroll
      for (int r = 0; r < 4; ++r) {
        int grow = mblk * 128 + wr * 64 + mi * 16 + g * 4 + r;
        hidb[(size_t)grow * 768 + jj] = f2b(gelu_exact(acc[mi][ni][r] + bs));
      }
  }
}

// ---------------- MLP fc2 + final residual -> d_out ----------------
__global__ __launch_bounds__(256) void fc2_n(const ushortT* __restrict__ hidb,
                                             const ushortT* __restrict__ fc2wb,
                                             const float* __restrict__ fc2b,
                                             const float* __restrict__ xout,
                                             float* __restrict__ out) {
  __shared__ alignas(16) ushortT Asl[64 * 64];
  __shared__ alignas(16) ushortT Bsl[192 * 64];
  CORE_IDS
  const int bx = blockIdx.x;
  ZERO_ACC(6)
  SETUP_A_ROWMAJOR(hidb, 768, bx)
  SETUP_B(fc2wb, 0, 768, 6)
  for (int ks = 0; ks < 12; ++ks) {
    STAGE_AB(6)
    CORE_MFMA(6)
  }
#pragma unroll
  for (int n = 0; n < 6; ++n) {
    int jj = wc * 96 + n * 16 + fr;
    float bs = fc2b[jj];
#pragma unroll
    for (int m = 0; m < 2; ++m)
#pragma unroll
      for (int r = 0; r < 4; ++r) {
        int grow = bx * 64 + wr * 32 + m * 16 + g * 4 + r;
        size_t addr = (size_t)grow * CC + jj;
        out[addr] = xout[addr] + acc[m][n][r] + bs;
      }
  }
}

// ---------------- launch ----------------
extern "C" void kernel_launch(void* const* d_in, const int* in_sizes, int n_in,
                              void* d_out, int out_size, void* d_ws, size_t ws_size,
                              hipStream_t stream) {
  const float* x     = (const float*)d_in[0];
  const float* y     = (const float*)d_in[1];
  const float* n1g   = (const float*)d_in[3];
  const float* n1b   = (const float*)d_in[4];
  const float* qkvw  = (const float*)d_in[5];
  const float* qkvb  = (const float*)d_in[6];
  const float* projw = (const float*)d_in[7];
  const float* projb = (const float*)d_in[8];
  const float* rpb   = (const float*)d_in[9];
  const float* n2g   = (const float*)d_in[10];
  const float* n2b   = (const float*)d_in[11];
  const float* fc1w  = (const float*)d_in[12];
  const float* fc1b  = (const float*)d_in[13];
  const float* fc2w  = (const float*)d_in[14];
  const float* fc2b  = (const float*)d_in[15];
  const float* w1    = (const float*)d_in[16];
  const float* b1    = (const float*)d_in[17];
  const float* w2    = (const float*)d_in[18];
  const float* b2    = (const float*)d_in[19];
  const float* ca1w  = (const float*)d_in[20];
  const float* ca1b  = (const float*)d_in[21];
  const float* ca2w  = (const float*)d_in[22];
  const float* ca2b  = (const float*)d_in[23];

  char* W = (char*)d_ws;
  float* out = (float*)d_out;

  ushortT* xnb  = (ushortT*)(W + 0);
  ushortT* ynb  = (ushortT*)(W + 16859136);
  ushortT* qbb  = (ushortT*)(W + 33718272);
  ushortT* kbb  = (ushortT*)(W + 50577408);
  ushortT* vbb  = (ushortT*)(W + 67436544);   // [wh][32][352] bf16
  ushortT* h1b  = (ushortT*)(W + 84738048);
  ushortT* h2b  = (ushortT*)(W + 90357760);   // bf16 (16.9 MB)
  float*   xo   = (float*)(W + 124076032);
  char*    SM   = W + 157794304;
  ushortT* qkvwb  = (ushortT*)(SM);
  ushortT* projwb = (ushortT*)(SM + 221184);
  ushortT* fc1wb  = (ushortT*)(SM + 294912);
  ushortT* fc2wb  = (ushortT*)(SM + 589824);
  ushortT* w1rb   = (ushortT*)(SM + 884736);
  ushortT* w2rb   = (ushortT*)(SM + 1548288);
  float*   rpb4   = (float*)(SM + 2211840);   // 2,973,696 B
  float*   av     = (float*)(SM + 5185536);   // 384 floats
  float*   part   = (float*)(SM + 5187072);   // 384 floats (pooled sums)
  float*   pc1    = (float*)(SM + 5319168);   // 4*CM*64 fp32
  ushortT* attnrb = xnb;
  ushortT* hlnb   = ynb;
  ushortT* hidb   = (ushortT*)(W + 33718272);

  // 0. zero pooled-sum accumulator
  hipMemsetAsync(part, 0, 2 * 192 * sizeof(float), stream);

  // 1. fused LN1(x,y) + weight prep + rpb4 table
  ln_prep_kernel<<<21952 + 5046, 256, 0, stream>>>(
      x, y, n1g, n1b, xnb, ynb,
      qkvw, projw, fc1w, fc2w, w1, w2, rpb,
      qkvwb, projwb, fc1wb, fc2wb, w1rb, w2rb, (float4*)rpb4);

  // 2. phase A: conv1 (split-K) + K/V proj + Q proj, one launch
  phaseA<<<1372 + 1029 + 686, 256, 0, stream>>>(xnb, ynb, qkvwb, qkvb, w1rb,
                                                qbb, kbb, vbb, pc1);

  // 3. conv1 combine -> h1b
  comb1_kernel<<<2744, 256, 0, stream>>>(pc1, b1, h1b);

  // 4. conv2 (bf16 + fused pool) || attention, one launch
  conv2attn<<<1029 + 1536, 256, 0, stream>>>(h1b, w2rb, b2, h2b, part,
                                             qbb, kbb, vbb, rpb4, attnrb);

  // 5. channel attention (tiny)
  ca_kernel<<<2, 192, 0, stream>>>(part, ca1w, ca1b, ca2w, ca2b, av);

  // 6. proj + window reverse + residual + fused LN2
  proj_ln<<<686, 256, 0, stream>>>(attnrb, projwb, projb, x, h2b, av, n2g, n2b, xo, hlnb);

  // 7. MLP
  fc1_128<<<343 * 6, 256, 0, stream>>>(hlnb, fc1wb, fc1b, hidb);
  fc2_n<<<686, 256, 0, stream>>>(hidb, fc2wb, fc2b, xo, out);
}

// Round 17
// 457.829 us; speedup vs baseline: 1.0168x; 1.0168x over previous
//
#include <hip/hip_runtime.h>
#include <math.h>

// ---------------- problem constants ----------------
constexpr int CB  = 2;
constexpr int CL  = 28 * 28 * 28;   // 21952
constexpr int CC  = 192;
constexpr int CM  = CB * CL;        // 43904 total tokens (= 128 windows * 343)

typedef unsigned short ushortT;
typedef __attribute__((ext_vector_type(8))) short bf16x8;
typedef __attribute__((ext_vector_type(4))) float f32x4;

// bijective XCD swizzle (m204)
__device__ __forceinline__ int xcd_swz(int lid, int total) {
  int q = total >> 3, r = total & 7;
  int x = lid & 7, s = lid >> 3;
  return (x < r ? x * (q + 1) : r * (q + 1) + (x - r) * q) + s;
}

__device__ __forceinline__ int tt_to_pos(int tt, int& b) {
  int bw = tt / 343;
  int n  = tt - bw * 343;
  b = bw >> 6;
  int wi = bw & 63;
  int n0 = n / 49, r = n - n0 * 49;
  int n1 = r / 7,  n2 = r - n1 * 7;
  int h = (wi >> 4) * 7 + n0;
  int w = ((wi >> 2) & 3) * 7 + n1;
  int t = (wi & 3) * 7 + n2;
  return (h * 28 + w) * 28 + t;
}

__device__ __forceinline__ float gelu_exact(float x) {
  return 0.5f * x * (1.0f + erff(x * 0.70710678118654752f));
}

__device__ __forceinline__ ushortT f2b(float x) {
  unsigned int u = __builtin_bit_cast(unsigned int, x);
  unsigned int r = (u + 0x7FFFu + ((u >> 16) & 1u)) >> 16;
  return (ushortT)r;
}
__device__ __forceinline__ float b2f(ushortT u) {
  return __builtin_bit_cast(float, (unsigned int)u << 16);
}

// async global->LDS, 16B per lane
typedef __attribute__((address_space(3))) unsigned int lds_uint;
typedef const __attribute__((address_space(1))) unsigned int glb_uint;
__device__ __forceinline__ void stage16(const ushortT* g, ushortT* l) {
#if defined(__has_builtin) && __has_builtin(__builtin_amdgcn_global_load_lds)
  __builtin_amdgcn_global_load_lds((glb_uint*)g, (lds_uint*)l, 16, 0, 0);
#else
  *(uint4*)l = *(const uint4*)g;
#endif
}

// swizzled LDS fragment pointer: 128B rows, 16B chunks, chunk ^= row&7
__device__ __forceinline__ const bf16x8* ldsfrag(const ushortT* base, int row, int chunk) {
  return (const bf16x8*)((const char*)base + row * 128 + ((chunk ^ (row & 7)) << 4));
}

// ---------------- fused: LayerNorm1 (x,y) + weight prep + rpb4 table ----------------
__global__ __launch_bounds__(256) void ln_prep_kernel(
    const float* __restrict__ in0, const float* __restrict__ in1,
    const float* __restrict__ g, const float* __restrict__ bb,
    ushortT* __restrict__ out0, ushortT* __restrict__ out1,
    const float* __restrict__ qkvw, const float* __restrict__ projw,
    const float* __restrict__ fc1w, const float* __restrict__ fc2w,
    const float* __restrict__ w1, const float* __restrict__ w2,
    const float* __restrict__ rpb,
    ushortT* qkvwb, ushortT* projwb, ushortT* fc1wb, ushortT* fc2wb,
    ushortT* w1rb, ushortT* w2rb, float4* rpb4) {
  int bid = blockIdx.x;
  if (bid < 21952) {
    int wave = threadIdx.x >> 6;
    int lane = threadIdx.x & 63;
    const float* in = (bid & 1) ? in1 : in0;
    ushortT* out = (bid & 1) ? out1 : out0;
    int row = (bid >> 1) * 4 + wave;
    const float* p = in + (size_t)row * CC;
    float v0 = p[lane], v1 = p[lane + 64], v2 = p[lane + 128];
    float s = v0 + v1 + v2;
    for (int o = 32; o; o >>= 1) s += __shfl_xor(s, o, 64);
    float mean = s * (1.0f / 192.0f);
    float d0 = v0 - mean, d1 = v1 - mean, d2 = v2 - mean;
    float qs = d0 * d0 + d1 * d1 + d2 * d2;
    for (int o = 32; o; o >>= 1) qs += __shfl_xor(qs, o, 64);
    float rs = rsqrtf(qs * (1.0f / 192.0f) + 1e-5f);
    ushortT* po = out + (size_t)row * CC;
    po[lane]       = f2b(d0 * rs * g[lane]       + bb[lane]);
    po[lane + 64]  = f2b(d1 * rs * g[lane + 64]  + bb[lane + 64]);
    po[lane + 128] = f2b(d2 * rs * g[lane + 128] + bb[lane + 128]);
    return;
  }
  int i = (bid - 21952) * 256 + threadIdx.x;
  if (i < 110592) { qkvwb[i] = f2b(qkvw[i]); return; }
  i -= 110592;
  if (i < 36864) { projwb[i] = f2b(projw[i]); return; }
  i -= 36864;
  if (i < 147456) { fc1wb[i] = f2b(fc1w[i]); return; }
  i -= 147456;
  if (i < 147456) { fc2wb[i] = f2b(fc2w[i]); return; }
  i -= 147456;
  if (i < 331776) {
    int o = i / 5184, r = i - o * 5184, tap = r / 192, c = r - tap * 192;
    w1rb[i] = f2b(w1[o * 5184 + c * 27 + tap]); return;
  }
  i -= 331776;
  if (i < 331776) {
    int o = i / 1728, r = i - o * 1728, tap = r / 64, c = r - tap * 64;
    w2rb[i] = f2b(w2[o * 1728 + c * 27 + tap]); return;
  }
  i -= 331776;
  if (i < 6 * 88 * 352) {
    int head = i / (88 * 352);
    int rem = i - head * 88 * 352;
    int qgrp = rem / 352, k = rem - qgrp * 352;
    float4 v = make_float4(0.f, 0.f, 0.f, 0.f);
    if (k < 343) {
      int b0 = k / 49, rb = k - b0 * 49; int b1 = rb / 7, b2 = rb - b1 * 7;
#pragma unroll
      for (int r = 0; r < 4; ++r) {
        int q = qgrp * 4 + r;
        if (q < 343) {
          int a0 = q / 49, ra = q - a0 * 49; int a1 = ra / 7, a2 = ra - a1 * 7;
          int ridx = ((a0 - b0 + 6) * 13 + (a1 - b1 + 6)) * 13 + (a2 - b2 + 6);
          (&v.x)[r] = rpb[ridx * 6 + head];
        }
      }
    }
    rpb4[i] = v;
  }
}

// ======== shared core macros ========
#define CORE_IDS \
  const int tid = threadIdx.x; \
  const int wave = tid >> 6, lane = tid & 63; \
  const int fr = lane & 15, g = lane >> 4; \
  const int wr = wave >> 1, wc = wave & 1;

#define ZERO_ACC(NF) \
  f32x4 acc[2][NF]; \
  _Pragma("unroll") \
  for (int m_ = 0; m_ < 2; ++m_) { \
    _Pragma("unroll") \
    for (int n_ = 0; n_ < NF; ++n_) acc[m_][n_] = (f32x4){0.f, 0.f, 0.f, 0.f}; \
  }

#define SETUP_A_ROWMAJOR(BASE, LDA, BX) \
  const ushortT* pa[2]; ushortT* la[2]; \
  _Pragma("unroll") \
  for (int i = 0; i < 2; ++i) { \
    int slot = i * 256 + tid; int row_ = slot >> 3; \
    int cc8 = ((slot & 7) ^ (row_ & 7)) * 8; \
    pa[i] = (BASE) + (size_t)((BX) * 64 + row_) * (LDA) + cc8; \
    la[i] = Asl + slot * 8; \
  }

#define SETUP_A_WINDOWED(BASE, BX) \
  const ushortT* pa[2]; ushortT* la[2]; \
  _Pragma("unroll") \
  for (int i = 0; i < 2; ++i) { \
    int slot = i * 256 + tid; int row_ = slot >> 3; \
    int cc8 = ((slot & 7) ^ (row_ & 7)) * 8; \
    int bq_; int pos_ = tt_to_pos((BX) * 64 + row_, bq_); \
    pa[i] = (BASE) + ((size_t)bq_ * CL + pos_) * CC + cc8; \
    la[i] = Asl + slot * 8; \
  }

#define SETUP_B(BASE, ROWOFF, LDB, NR) \
  const ushortT* pb[NR]; ushortT* lb[NR]; \
  _Pragma("unroll") \
  for (int i = 0; i < NR; ++i) { \
    int slot = i * 256 + tid; int row_ = slot >> 3; \
    int cc8 = ((slot & 7) ^ (row_ & 7)) * 8; \
    pb[i] = (BASE) + (size_t)((ROWOFF) + row_) * (LDB) + cc8; \
    lb[i] = Bsl + slot * 8; \
  }

#define STAGE_AB(NR) \
  _Pragma("unroll") \
  for (int i = 0; i < 2; ++i) { stage16(pa[i], la[i]); pa[i] += 64; } \
  _Pragma("unroll") \
  for (int i = 0; i < NR; ++i) { stage16(pb[i], lb[i]); pb[i] += 64; }

#define CORE_MFMA(NF) \
  __syncthreads(); \
  _Pragma("unroll") \
  for (int kk = 0; kk < 2; ++kk) { \
    bf16x8 a0 = *ldsfrag(Asl, wr * 32 + fr, kk * 4 + g); \
    bf16x8 a1 = *ldsfrag(Asl, wr * 32 + 16 + fr, kk * 4 + g); \
    _Pragma("unroll") \
    for (int n_ = 0; n_ < NF; ++n_) { \
      bf16x8 bn = *ldsfrag(Bsl, wc * ((NF) * 16) + n_ * 16 + fr, kk * 4 + g); \
      acc[0][n_] = __builtin_amdgcn_mfma_f32_16x16x32_bf16(a0, bn, acc[0][n_], 0, 0, 0); \
      acc[1][n_] = __builtin_amdgcn_mfma_f32_16x16x32_bf16(a1, bn, acc[1][n_], 0, 0, 0); \
    } \
  } \
  __syncthreads();

// ======== 128x128 core (uses local `mblk`) ========
#define M128_ZERO \
  f32x4 acc[4][4]; \
  _Pragma("unroll") \
  for (int m_ = 0; m_ < 4; ++m_) \
    _Pragma("unroll") \
    for (int n_ = 0; n_ < 4; ++n_) acc[m_][n_] = (f32x4){0.f, 0.f, 0.f, 0.f};

#define M128_SETUP_A_ROWMAJOR(BASE, LDA) \
  const ushortT* pa[4]; ushortT* la[4]; \
  _Pragma("unroll") \
  for (int i = 0; i < 4; ++i) { \
    int slot = i * 256 + tid; int row_ = slot >> 3; \
    int cc8 = ((slot & 7) ^ (row_ & 7)) * 8; \
    pa[i] = (BASE) + (size_t)(mblk * 128 + row_) * (LDA) + cc8; \
    la[i] = Asl + slot * 8; \
  }

#define M128_SETUP_A_WINDOWED(BASE) \
  const ushortT* pa[4]; ushortT* la[4]; \
  _Pragma("unroll") \
  for (int i = 0; i < 4; ++i) { \
    int slot = i * 256 + tid; int row_ = slot >> 3; \
    int cc8 = ((slot & 7) ^ (row_ & 7)) * 8; \
    int bq_; int pos_ = tt_to_pos(mblk * 128 + row_, bq_); \
    pa[i] = (BASE) + ((size_t)bq_ * CL + pos_) * CC + cc8; \
    la[i] = Asl + slot * 8; \
  }

#define M128_SETUP_B(BASE, ROWOFF, LDB) \
  const ushortT* pb[4]; ushortT* lb[4]; \
  _Pragma("unroll") \
  for (int i = 0; i < 4; ++i) { \
    int slot = i * 256 + tid; int row_ = slot >> 3; \
    int cc8 = ((slot & 7) ^ (row_ & 7)) * 8; \
    pb[i] = (BASE) + (size_t)((ROWOFF) + row_) * (LDB) + cc8; \
    lb[i] = Bsl + slot * 8; \
  }

#define M128_STAGE \
  { _Pragma("unroll") \
    for (int i = 0; i < 4; ++i) { stage16(pa[i], la[i]); pa[i] += 64; } \
    _Pragma("unroll") \
    for (int i = 0; i < 4; ++i) { stage16(pb[i], lb[i]); pb[i] += 64; } }

#define M128_MFMA \
  { _Pragma("unroll") \
    for (int kk = 0; kk < 2; ++kk) { \
      bf16x8 am[4], bn[4]; \
      _Pragma("unroll") \
      for (int m_ = 0; m_ < 4; ++m_) am[m_] = *ldsfrag(Asl, wr * 64 + m_ * 16 + fr, kk * 4 + g); \
      _Pragma("unroll") \
      for (int n_ = 0; n_ < 4; ++n_) bn[n_] = *ldsfrag(Bsl, wc * 64 + n_ * 16 + fr, kk * 4 + g); \
      _Pragma("unroll") \
      for (int m_ = 0; m_ < 4; ++m_) \
        _Pragma("unroll") \
        for (int n_ = 0; n_ < 4; ++n_) \
          acc[m_][n_] = __builtin_amdgcn_mfma_f32_16x16x32_bf16(am[m_], bn[n_], acc[m_][n_], 0, 0, 0); \
    } }

#define M128_LOOP(KS) \
  _Pragma("unroll") \
  for (int ks = 0; ks < (KS); ++ks) { \
    M128_STAGE \
    __syncthreads(); \
    M128_MFMA \
    __syncthreads(); \
  }

// ---------------- device bodies ----------------
__device__ __forceinline__ void gemmq_body(int bx, ushortT* Asl, ushortT* Bsl,
                                           const ushortT* __restrict__ xnb,
                                           const ushortT* __restrict__ qkvwb,
                                           const float* __restrict__ qkvb,
                                           ushortT* __restrict__ qout) {
  CORE_IDS
  ZERO_ACC(6)
  SETUP_A_WINDOWED(xnb, bx)
  SETUP_B(qkvwb, 0, 192, 6)
  for (int ks = 0; ks < 3; ++ks) {
    STAGE_AB(6)
    CORE_MFMA(6)
  }
#pragma unroll
  for (int n = 0; n < 6; ++n) {
    int jj = wc * 96 + n * 16 + fr;
    int head = jj >> 5, d = jj & 31;
    float bias = qkvb[jj];
#pragma unroll
    for (int m = 0; m < 2; ++m)
#pragma unroll
      for (int r = 0; r < 4; ++r) {
        int tt = bx * 64 + wr * 32 + m * 16 + g * 4 + r;
        int bw = tt / 343, nn = tt - bw * 343;
        qout[(((size_t)bw * 6 + head) * 343 + nn) * 32 + d] =
            f2b((acc[m][n][r] + bias) * 0.17677669529663687f);
      }
  }
}

__device__ __forceinline__ void kv_body(int bx, ushortT* Asl, ushortT* Bsl,
                                        const ushortT* __restrict__ ynb,
                                        const ushortT* __restrict__ qkvwb,
                                        const float* __restrict__ qkvb,
                                        ushortT* __restrict__ kout,
                                        ushortT* __restrict__ vout) {
  CORE_IDS
  const int wid = xcd_swz(bx, 343 * 3);
  const int mblk = wid / 3;
  const int jb = (wid - mblk * 3) * 128;
  M128_ZERO
  M128_SETUP_A_WINDOWED(ynb)
  M128_SETUP_B(qkvwb, 192 + jb, 192)
  M128_LOOP(3)
#pragma unroll
  for (int ni = 0; ni < 4; ++ni) {
    int jj = jb + wc * 64 + ni * 16 + fr;
    float bias = qkvb[192 + jj];
#pragma unroll
    for (int mi = 0; mi < 4; ++mi)
#pragma unroll
      for (int r = 0; r < 4; ++r) {
        int tt = mblk * 128 + wr * 64 + mi * 16 + g * 4 + r;
        int bw = tt / 343, nn = tt - bw * 343;
        float val = acc[mi][ni][r] + bias;
        if (jj < 192) {
          int head = jj >> 5, d = jj & 31;
          kout[(((size_t)bw * 6 + head) * 343 + nn) * 32 + d] = f2b(val);
        } else {
          int jv = jj - 192;
          int head = jv >> 5, d = jv & 31;
          vout[((size_t)bw * 6 + head) * 11264 + (size_t)d * 352 + nn] = f2b(val);
        }
      }
  }
}

// conv body: MODE 2 = split-K fp32 partial (conv1), MODE 0 = bf16+bias+pool (conv2)
template <int CIN, int COUTT, int MODE>
__device__ __forceinline__ void conv_body(int bx, ushortT* Asl, ushortT* Bsl,
                                          const ushortT* __restrict__ src,
                                          const ushortT* __restrict__ wrw,
                                          const float* __restrict__ bias,
                                          void* __restrict__ dst,
                                          float* __restrict__ part) {
  constexpr int KT = 27 * CIN;
  constexpr int KN = KT / 64;
  constexpr int NY = (MODE == 2) ? 4 : (COUTT / 64);
  constexpr int NBLK = 343 * NY;
  const int tid = threadIdx.x;
  const int wave = tid >> 6, lane = tid & 63;
  const int fr = lane & 15, g = lane >> 4;
  const int wid = xcd_swz(bx, NBLK);
  const int mblk = wid / NY;
  const int ysub = wid - mblk * NY;
  f32x4 acc[2][4];
#pragma unroll
  for (int m = 0; m < 2; ++m)
#pragma unroll
    for (int n = 0; n < 4; ++n) acc[m][n] = (f32x4){0.f, 0.f, 0.f, 0.f};

  const int kb = (MODE == 2) ? (ysub * KN) / 4 : 0;
  const int ke = (MODE == 2) ? ((ysub + 1) * KN) / 4 : KN;
  const int jbN = (MODE == 0) ? ysub * 64 : 0;

  const ushortT* srcb[4];
  ushortT* la[4];
  unsigned vmask[4];
#pragma unroll
  for (int i = 0; i < 4; ++i) {
    int slot = i * 256 + tid; int row_ = slot >> 3;
    int cc8 = ((slot & 7) ^ (row_ & 7)) * 8;
    int grow = mblk * 128 + row_;
    int bbq = grow / CL;
    int pos = grow - bbq * CL;
    int h = pos / 784, w = (pos / 28) % 28, t = pos % 28;
    unsigned vm = 0;
#pragma unroll
    for (int tap = 0; tap < 27; ++tap) {
      int dh = tap / 9 - 1, dw = (tap / 3) % 3 - 1, dt = tap % 3 - 1;
      bool ok = ((unsigned)(h + dh) < 28u) && ((unsigned)(w + dw) < 28u) &&
                ((unsigned)(t + dt) < 28u);
      vm |= (unsigned)ok << tap;
    }
    vmask[i] = vm;
    srcb[i] = src + ((size_t)bbq * CL + pos) * CIN + cc8;
    la[i] = Asl + slot * 8;
  }
  const ushortT* pb[2]; ushortT* lb[2];
#pragma unroll
  for (int i = 0; i < 2; ++i) {
    int slot = i * 256 + tid; int row_ = slot >> 3;
    int cc8 = ((slot & 7) ^ (row_ & 7)) * 8;
    pb[i] = wrw + (size_t)(jbN + row_) * KT + kb * 64 + cc8;
    lb[i] = Bsl + slot * 8;
  }

  auto loadA = [&](int ks, int i) -> uint4 {
    int tap, cb;
    if (CIN == 64) { tap = ks; cb = 0; }
    else           { tap = ks / 3; cb = (ks - tap * 3) * 64; }
    int off = ((tap / 9 - 1) * 784 + ((tap / 3) % 3 - 1) * 28 + (tap % 3 - 1)) * CIN + cb;
    uint4 v = make_uint4(0u, 0u, 0u, 0u);
    if ((vmask[i] >> tap) & 1u) v = *(const uint4*)(srcb[i] + off);
    return v;
  };

  uint4 vr[4];
#pragma unroll
  for (int i = 0; i < 4; ++i) vr[i] = loadA(kb, i);
  for (int ks = kb; ks < ke; ++ks) {
#pragma unroll
    for (int i = 0; i < 4; ++i) *(uint4*)la[i] = vr[i];
#pragma unroll
    for (int i = 0; i < 2; ++i) { stage16(pb[i], lb[i]); pb[i] += 64; }
    __syncthreads();
    bool more = (ks + 1 < ke);
    if (more) {
#pragma unroll
      for (int i = 0; i < 4; ++i) vr[i] = loadA(ks + 1, i);
    }
#pragma unroll
    for (int kk = 0; kk < 2; ++kk) {
      bf16x8 a0 = *ldsfrag(Asl, wave * 32 + fr, kk * 4 + g);
      bf16x8 a1 = *ldsfrag(Asl, wave * 32 + 16 + fr, kk * 4 + g);
#pragma unroll
      for (int n = 0; n < 4; ++n) {
        bf16x8 bn = *ldsfrag(Bsl, n * 16 + fr, kk * 4 + g);
        acc[0][n] = __builtin_amdgcn_mfma_f32_16x16x32_bf16(a0, bn, acc[0][n], 0, 0, 0);
        acc[1][n] = __builtin_amdgcn_mfma_f32_16x16x32_bf16(a1, bn, acc[1][n], 0, 0, 0);
      }
    }
    __syncthreads();
  }
  if (MODE == 2) {
#pragma unroll
    for (int n = 0; n < 4; ++n) {
      int jj = n * 16 + fr;
#pragma unroll
      for (int m = 0; m < 2; ++m)
#pragma unroll
        for (int r = 0; r < 4; ++r) {
          int grow = mblk * 128 + wave * 32 + m * 16 + g * 4 + r;
          ((float*)dst)[((size_t)ysub * CM + grow) * 64 + jj] = acc[m][n][r];
        }
    }
  } else {
    float* red = (float*)Asl;
#pragma unroll
    for (int n = 0; n < 4; ++n) {
      int jj = n * 16 + fr;
      float bs = bias[jbN + jj];
      float s0 = 0.f, s1 = 0.f;
#pragma unroll
      for (int m = 0; m < 2; ++m)
#pragma unroll
        for (int r = 0; r < 4; ++r) {
          int grow = mblk * 128 + wave * 32 + m * 16 + g * 4 + r;
          float v = acc[m][n][r] + bs;
          ((ushortT*)dst)[(size_t)grow * COUTT + jbN + jj] = f2b(v);
          if (grow < CL) s0 += v; else s1 += v;
        }
      s0 += __shfl_xor(s0, 16, 64); s0 += __shfl_xor(s0, 32, 64);
      s1 += __shfl_xor(s1, 16, 64); s1 += __shfl_xor(s1, 32, 64);
      if (g == 0) {
        red[((wave * 4 + n) * 16 + fr) * 2 + 0] = s0;
        red[((wave * 4 + n) * 16 + fr) * 2 + 1] = s1;
      }
    }
    __syncthreads();
    if (tid < 128) {
      int chl = tid >> 1, bsel = tid & 1;
      float s = 0.f;
#pragma unroll
      for (int wv = 0; wv < 4; ++wv)
        s += red[((wv * 4 + (chl >> 4)) * 16 + (chl & 15)) * 2 + bsel];
      if (s != 0.0f) atomicAdd(&part[bsel * 192 + jbN + chl], s);
    }
  }
}

// attn body (no-max softmax, LDS-staged)
constexpr int KP  = 36;
constexpr int VP  = 356;
constexpr int VP2 = 200;

__device__ __forceinline__ void attn_body(int bx, ushortT* Kl, ushortT* Vt, ushortT* Pl,
                                          const ushortT* __restrict__ qb,
                                          const ushortT* __restrict__ kb,
                                          const ushortT* __restrict__ vb,
                                          const float* __restrict__ rpb4,
                                          ushortT* __restrict__ aout) {
  const int tid = threadIdx.x;
  const int wave = tid >> 6, lane = tid & 63;
  const int fr = lane & 15, g = lane >> 4, fk = g * 8;
  const int wid = xcd_swz(bx, 768 * 2);
  const int wh = wid >> 1;
  const int qhalf = wid & 1;
  const int bw = wh / 6, head = wh - bw * 6;
  const ushortT* kp = kb + (size_t)wh * 343 * 32;
  const ushortT* vp = vb + (size_t)wh * 11264;
  const ushortT* qp = qb + (size_t)wh * 343 * 32;
  const f32x4* bp4 = (const f32x4*)rpb4 + (size_t)head * 88 * 352;

  for (int c = tid; c < 1372; c += 256) {
    int key = c >> 2, pp = c & 3;
    *(uint4*)&Kl[key * KP + pp * 8] = *(const uint4*)(kp + (size_t)c * 8);
  }
  for (int c = tid; c < 1408; c += 256) {
    int d = c / 44, p = c - d * 44;
    *(uint4*)&Vt[d * VP + p * 8] = *(const uint4*)(vp + (size_t)c * 8);
  }
  __syncthreads();

  for (int qi = 0; qi < 3; ++qi) {
    const int q0 = (qhalf * 3 + qi) * 64;

    int qrow = q0 + wave * 16 + fr; if (qrow > 342) qrow = 342;
    bf16x8 aq = *(const bf16x8*)(qp + (size_t)qrow * 32 + fk);

    const int qgrp = (q0 + wave * 16) / 4 + g;
    f32x4 sc[22];
#pragma unroll
    for (int t = 0; t < 22; ++t) {
      f32x4 cini = bp4[(size_t)qgrp * 352 + t * 16 + fr];
      bf16x8 bk = *(const bf16x8*)&Kl[(t * 16 + fr) * KP + fk];
      sc[t] = __builtin_amdgcn_mfma_f32_16x16x32_bf16(aq, bk, cini, 0, 0, 0);
    }
    if (fr > 6) { sc[21][0] = -1e30f; sc[21][1] = -1e30f; sc[21][2] = -1e30f; sc[21][3] = -1e30f; }

    float rinv[4];
#pragma unroll
    for (int r = 0; r < 4; ++r) {
      float sum = 0.0f;
#pragma unroll
      for (int t = 0; t < 22; ++t) {
        float e = __expf(sc[t][r]);
        sc[t][r] = e;
        sum += e;
      }
      sum += __shfl_xor(sum, 1, 64); sum += __shfl_xor(sum, 2, 64);
      sum += __shfl_xor(sum, 4, 64); sum += __shfl_xor(sum, 8, 64);
      rinv[r] = 1.0f / sum;
    }

    f32x4 o0 = {0.f, 0.f, 0.f, 0.f}, o1 = {0.f, 0.f, 0.f, 0.f};

#pragma unroll
    for (int t = 0; t < 12; ++t)
#pragma unroll
      for (int r = 0; r < 4; ++r)
        Pl[(wave * 16 + g * 4 + r) * VP2 + t * 16 + fr] = f2b(sc[t][r]);
    asm volatile("s_waitcnt lgkmcnt(0)" ::: "memory");
#pragma unroll
    for (int s = 0; s < 6; ++s) {
      bf16x8 ap  = *(const bf16x8*)&Pl[(wave * 16 + fr) * VP2 + s * 32 + fk];
      bf16x8 bv0 = *(const bf16x8*)&Vt[fr * VP + s * 32 + fk];
      bf16x8 bv1 = *(const bf16x8*)&Vt[(16 + fr) * VP + s * 32 + fk];
      o0 = __builtin_amdgcn_mfma_f32_16x16x32_bf16(ap, bv0, o0, 0, 0, 0);
      o1 = __builtin_amdgcn_mfma_f32_16x16x32_bf16(ap, bv1, o1, 0, 0, 0);
    }
    asm volatile("s_waitcnt lgkmcnt(0)" ::: "memory");

#pragma unroll
    for (int t = 12; t < 22; ++t)
#pragma unroll
      for (int r = 0; r < 4; ++r)
        Pl[(wave * 16 + g * 4 + r) * VP2 + (t - 12) * 16 + fr] = f2b(sc[t][r]);
    asm volatile("s_waitcnt lgkmcnt(0)" ::: "memory");
#pragma unroll
    for (int s = 0; s < 5; ++s) {
      bf16x8 ap  = *(const bf16x8*)&Pl[(wave * 16 + fr) * VP2 + s * 32 + fk];
      bf16x8 bv0 = *(const bf16x8*)&Vt[fr * VP + 192 + s * 32 + fk];
      bf16x8 bv1 = *(const bf16x8*)&Vt[(16 + fr) * VP + 192 + s * 32 + fk];
      o0 = __builtin_amdgcn_mfma_f32_16x16x32_bf16(ap, bv0, o0, 0, 0, 0);
      o1 = __builtin_amdgcn_mfma_f32_16x16x32_bf16(ap, bv1, o1, 0, 0, 0);
    }
    asm volatile("s_waitcnt lgkmcnt(0)" ::: "memory");

#pragma unroll
    for (int r = 0; r < 4; ++r) {
      int q = q0 + wave * 16 + g * 4 + r;
      if (q < 343) {
        float ri = rinv[r];
        size_t base = ((size_t)bw * 343 + q) * 192 + head * 32;
        aout[base + fr]      = f2b(o0[r] * ri);
        aout[base + 16 + fr] = f2b(o1[r] * ri);
      }
    }
  }
}

// ---------------- phase A: conv1 + kv + gemm_q (homogeneous 32 KB LDS, one launch) ----------------
__global__ __launch_bounds__(256) void phaseA(const ushortT* __restrict__ xnb,
                                              const ushortT* __restrict__ ynb,
                                              const ushortT* __restrict__ qkvwb,
                                              const float* __restrict__ qkvb,
                                              const ushortT* __restrict__ w1rb,
                                              ushortT* __restrict__ qout,
                                              ushortT* __restrict__ kout,
                                              ushortT* __restrict__ vout,
                                              float* __restrict__ pc1) {
  __shared__ alignas(16) ushortT SH[16384];   // 32 KB
  const int bid = blockIdx.x;
  if (bid < 1372) {
    conv_body<192, 64, 2>(bid, SH, SH + 8192, xnb, w1rb, nullptr, pc1, nullptr);
  } else if (bid < 2401) {
    kv_body(bid - 1372, SH, SH + 8192, ynb, qkvwb, qkvb, kout, vout);
  } else {
    gemmq_body(bid - 2401, SH, SH + 4096, xnb, qkvwb, qkvb, qout);
  }
}

// ---------------- conv1 combine ----------------
__global__ __launch_bounds__(256) void comb1_kernel(const float* __restrict__ pc,
                                                    const float* __restrict__ b1,
                                                    ushortT* __restrict__ h1b) {
  size_t idx = ((size_t)blockIdx.x * 256 + threadIdx.x) * 4;
  float4 a = *(const float4*)(pc + idx);
  float4 b = *(const float4*)(pc + (size_t)CM * 64 + idx);
  float4 c = *(const float4*)(pc + (size_t)CM * 128 + idx);
  float4 d = *(const float4*)(pc + (size_t)CM * 192 + idx);
  int c0 = (int)(idx & 63);
  ushortT o0 = f2b(gelu_exact(a.x + b.x + c.x + d.x + b1[c0 + 0]));
  ushortT o1 = f2b(gelu_exact(a.y + b.y + c.y + d.y + b1[c0 + 1]));
  ushortT o2 = f2b(gelu_exact(a.z + b.z + c.z + d.z + b1[c0 + 2]));
  ushortT o3 = f2b(gelu_exact(a.w + b.w + c.w + d.w + b1[c0 + 3]));
  unsigned int w0 = (unsigned int)o0 | ((unsigned int)o1 << 16);
  unsigned int w1 = (unsigned int)o2 | ((unsigned int)o3 << 16);
  *(uint2*)&h1b[idx] = make_uint2(w0, w1);
}

// ---------------- conv2 standalone (24 KB LDS) ----------------
__global__ __launch_bounds__(256) void conv2_kernel(const ushortT* __restrict__ h1b,
                                                    const ushortT* __restrict__ w2rb,
                                                    const float* __restrict__ b2,
                                                    ushortT* __restrict__ h2b,
                                                    float* __restrict__ part) {
  __shared__ alignas(16) ushortT Asl[8192];
  __shared__ alignas(16) ushortT Bsl[4096];
  conv_body<64, 192, 0>(blockIdx.x, Asl, Bsl, h1b, w2rb, b2, h2b, part);
}

// ---------------- attention (72 KB LDS) + ca tail blocks ----------------
__global__ __launch_bounds__(256) void attn_ca(const ushortT* __restrict__ qb,
                                               const ushortT* __restrict__ kb,
                                               const ushortT* __restrict__ vb,
                                               const float* __restrict__ rpb4,
                                               ushortT* __restrict__ aout,
                                               const float* __restrict__ part,
                                               const float* __restrict__ ca1w,
                                               const float* __restrict__ ca1b,
                                               const float* __restrict__ ca2w,
                                               const float* __restrict__ ca2b,
                                               float* __restrict__ av) {
  __shared__ alignas(16) ushortT SH[36864];   // 72 KB
  const int tid = threadIdx.x;
  if (blockIdx.x >= 1536) {
    int b = blockIdx.x - 1536;
    float* pl = (float*)SH;
    float* hid = pl + 192;
    if (tid < 192) pl[tid] = part[b * 192 + tid] * (1.0f / (float)CL);
    __syncthreads();
    if (tid < 12) {
      float t = ca1b[tid];
      for (int i = 0; i < 192; ++i) t += ca1w[tid * 192 + i] * pl[i];
      hid[tid] = fmaxf(t, 0.0f);
    }
    __syncthreads();
    if (tid < 192) {
      float t = ca2b[tid];
#pragma unroll
      for (int j = 0; j < 12; ++j) t += ca2w[tid * 12 + j] * hid[j];
      av[b * 192 + tid] = 1.0f / (1.0f + __expf(-t));
    }
    return;
  }
  attn_body(blockIdx.x, SH, SH + 12672, SH + 24064, qb, kb, vb, rpb4, aout);
}

// ---------------- proj + window-reverse + residual + FUSED LayerNorm2 ----------------
__global__ __launch_bounds__(256) void proj_ln(const ushortT* __restrict__ attnrb,
                                               const ushortT* __restrict__ projwb,
                                               const float* __restrict__ projb,
                                               const float* __restrict__ x0,
                                               const ushortT* __restrict__ h2b,
                                               const float* __restrict__ cav,
                                               const float* __restrict__ n2g,
                                               const float* __restrict__ n2b,
                                               float* __restrict__ xout,
                                               ushortT* __restrict__ hlnb) {
  __shared__ alignas(16) ushortT Asl[64 * 64];
  __shared__ alignas(16) ushortT Bsl[192 * 64];
  CORE_IDS
  const int bx = blockIdx.x;
  ZERO_ACC(6)
  SETUP_A_ROWMAJOR(attnrb, CC, bx)
  SETUP_B(projwb, 0, 192, 6)
  for (int ks = 0; ks < 3; ++ks) {
    STAGE_AB(6)
    CORE_MFMA(6)
  }
  size_t sbase[2][4];
#pragma unroll
  for (int m = 0; m < 2; ++m)
#pragma unroll
    for (int r = 0; r < 4; ++r) {
      int tt = bx * 64 + wr * 32 + m * 16 + g * 4 + r;
      int bq_;
      int pos_ = tt_to_pos(tt, bq_);
      size_t base = ((size_t)bq_ * CL + pos_) * CC;
      sbase[m][r] = base;
#pragma unroll
      for (int n = 0; n < 6; ++n) {
        int jj = wc * 96 + n * 16 + fr;
        size_t addr = base + jj;
        float v = x0[addr] + acc[m][n][r] + projb[jj] + b2f(h2b[addr]) * cav[bq_ * 192 + jj];
        acc[m][n][r] = v;
        xout[addr] = v;
      }
    }
  float* stats = (float*)Asl;
#pragma unroll
  for (int m = 0; m < 2; ++m)
#pragma unroll
    for (int r = 0; r < 4; ++r) {
      float ps = 0.f, ps2 = 0.f;
#pragma unroll
      for (int n = 0; n < 6; ++n) { float v = acc[m][n][r]; ps += v; ps2 += v * v; }
      ps  += __shfl_xor(ps, 1, 64);  ps2 += __shfl_xor(ps2, 1, 64);
      ps  += __shfl_xor(ps, 2, 64);  ps2 += __shfl_xor(ps2, 2, 64);
      ps  += __shfl_xor(ps, 4, 64);  ps2 += __shfl_xor(ps2, 4, 64);
      ps  += __shfl_xor(ps, 8, 64);  ps2 += __shfl_xor(ps2, 8, 64);
      if (fr == 0) {
        int lrow = wr * 32 + m * 16 + g * 4 + r;
        stats[lrow * 4 + wc * 2]     = ps;
        stats[lrow * 4 + wc * 2 + 1] = ps2;
      }
    }
  __syncthreads();
#pragma unroll
  for (int m = 0; m < 2; ++m)
#pragma unroll
    for (int r = 0; r < 4; ++r) {
      int lrow = wr * 32 + m * 16 + g * 4 + r;
      float s  = stats[lrow * 4]     + stats[lrow * 4 + 2];
      float s2 = stats[lrow * 4 + 1] + stats[lrow * 4 + 3];
      float mean = s * (1.0f / 192.0f);
      float var  = s2 * (1.0f / 192.0f) - mean * mean;
      float rs = rsqrtf(var + 1e-5f);
      ushortT* po = hlnb + sbase[m][r];
#pragma unroll
      for (int n = 0; n < 6; ++n) {
        int jj = wc * 96 + n * 16 + fr;
        po[jj] = f2b((acc[m][n][r] - mean) * rs * n2g[jj] + n2b[jj]);
      }
    }
}

// ---------------- MLP fc1 (128x128 core, XCD-swizzled) ----------------
__global__ __launch_bounds__(256) void fc1_128(const ushortT* __restrict__ hlnb,
                                               const ushortT* __restrict__ fc1wb,
                                               const float* __restrict__ fc1b,
                                               ushortT* __restrict__ hidb) {
  __shared__ alignas(16) ushortT Asl[8192];
  __shared__ alignas(16) ushortT Bsl[8192];
  CORE_IDS
  const int wid = xcd_swz(blockIdx.x, 343 * 6);
  const int mblk = wid / 6;
  const int jb = (wid - mblk * 6) * 128;
  M128_ZERO
  M128_SETUP_A_ROWMAJOR(hlnb, CC)
  M128_SETUP_B(fc1wb, jb, 192)
  M128_LOOP(3)
#pragma unroll
  for (int ni = 0; ni < 4; ++ni) {
    int jj = jb + wc * 64 + ni * 16 + fr;
    float bs = fc1b[jj];
#pragma unroll
    for (int mi = 0; mi < 4; ++mi)
#pragma unroll
      for (int r = 0; r < 4; ++r) {
        int grow = mblk * 128 + wr * 64 + mi * 16 + g * 4 + r;
        hidb[(size_t)grow * 768 + jj] = f2b(gelu_exact(acc[mi][ni][r] + bs));
      }
  }
}

// ---------------- MLP fc2 + final residual -> d_out ----------------
__global__ __launch_bounds__(256) void fc2_n(const ushortT* __restrict__ hidb,
                                             const ushortT* __restrict__ fc2wb,
                                             const float* __restrict__ fc2b,
                                             const float* __restrict__ xout,
                                             float* __restrict__ out) {
  __shared__ alignas(16) ushortT Asl[64 * 64];
  __shared__ alignas(16) ushortT Bsl[192 * 64];
  CORE_IDS
  const int bx = blockIdx.x;
  ZERO_ACC(6)
  SETUP_A_ROWMAJOR(hidb, 768, bx)
  SETUP_B(fc2wb, 0, 768, 6)
  for (int ks = 0; ks < 12; ++ks) {
    STAGE_AB(6)
    CORE_MFMA(6)
  }
#pragma unroll
  for (int n = 0; n < 6; ++n) {
    int jj = wc * 96 + n * 16 + fr;
    float bs = fc2b[jj];
#pragma unroll
    for (int m = 0; m < 2; ++m)
#pragma unroll
      for (int r = 0; r < 4; ++r) {
        int grow = bx * 64 + wr * 32 + m * 16 + g * 4 + r;
        size_t addr = (size_t)grow * CC + jj;
        out[addr] = xout[addr] + acc[m][n][r] + bs;
      }
  }
}

// ---------------- launch ----------------
extern "C" void kernel_launch(void* const* d_in, const int* in_sizes, int n_in,
                              void* d_out, int out_size, void* d_ws, size_t ws_size,
                              hipStream_t stream) {
  const float* x     = (const float*)d_in[0];
  const float* y     = (const float*)d_in[1];
  const float* n1g   = (const float*)d_in[3];
  const float* n1b   = (const float*)d_in[4];
  const float* qkvw  = (const float*)d_in[5];
  const float* qkvb  = (const float*)d_in[6];
  const float* projw = (const float*)d_in[7];
  const float* projb = (const float*)d_in[8];
  const float* rpb   = (const float*)d_in[9];
  const float* n2g   = (const float*)d_in[10];
  const float* n2b   = (const float*)d_in[11];
  const float* fc1w  = (const float*)d_in[12];
  const float* fc1b  = (const float*)d_in[13];
  const float* fc2w  = (const float*)d_in[14];
  const float* fc2b  = (const float*)d_in[15];
  const float* w1    = (const float*)d_in[16];
  const float* b1    = (const float*)d_in[17];
  const float* w2    = (const float*)d_in[18];
  const float* b2    = (const float*)d_in[19];
  const float* ca1w  = (const float*)d_in[20];
  const float* ca1b  = (const float*)d_in[21];
  const float* ca2w  = (const float*)d_in[22];
  const float* ca2b  = (const float*)d_in[23];

  char* W = (char*)d_ws;
  float* out = (float*)d_out;

  ushortT* xnb  = (ushortT*)(W + 0);
  ushortT* ynb  = (ushortT*)(W + 16859136);
  ushortT* qbb  = (ushortT*)(W + 33718272);
  ushortT* kbb  = (ushortT*)(W + 50577408);
  ushortT* vbb  = (ushortT*)(W + 67436544);   // [wh][32][352] bf16
  ushortT* h1b  = (ushortT*)(W + 84738048);
  ushortT* h2b  = (ushortT*)(W + 90357760);   // bf16 (16.9 MB)
  float*   xo   = (float*)(W + 124076032);
  char*    SM   = W + 157794304;
  ushortT* qkvwb  = (ushortT*)(SM);
  ushortT* projwb = (ushortT*)(SM + 221184);
  ushortT* fc1wb  = (ushortT*)(SM + 294912);
  ushortT* fc2wb  = (ushortT*)(SM + 589824);
  ushortT* w1rb   = (ushortT*)(SM + 884736);
  ushortT* w2rb   = (ushortT*)(SM + 1548288);
  float*   rpb4   = (float*)(SM + 2211840);   // 2,973,696 B
  float*   av     = (float*)(SM + 5185536);   // 384 floats
  float*   part   = (float*)(SM + 5187072);   // 384 floats (pooled sums)
  float*   pc1    = (float*)(SM + 5319168);   // 4*CM*64 fp32
  ushortT* attnrb = xnb;
  ushortT* hlnb   = ynb;
  ushortT* hidb   = (ushortT*)(W + 33718272);

  // 0. zero pooled-sum accumulator
  hipMemsetAsync(part, 0, 2 * 192 * sizeof(float), stream);

  // 1. fused LN1(x,y) + weight prep + rpb4 table
  ln_prep_kernel<<<21952 + 5046, 256, 0, stream>>>(
      x, y, n1g, n1b, xnb, ynb,
      qkvw, projw, fc1w, fc2w, w1, w2, rpb,
      qkvwb, projwb, fc1wb, fc2wb, w1rb, w2rb, (float4*)rpb4);

  // 2. phase A: conv1 (split-K) + K/V proj + Q proj (homogeneous LDS)
  phaseA<<<1372 + 1029 + 686, 256, 0, stream>>>(xnb, ynb, qkvwb, qkvb, w1rb,
                                                qbb, kbb, vbb, pc1);

  // 3. conv1 combine -> h1b
  comb1_kernel<<<2744, 256, 0, stream>>>(pc1, b1, h1b);

  // 4. conv2 (standalone, 24 KB LDS) -> h2b + pooled sums
  conv2_kernel<<<1029, 256, 0, stream>>>(h1b, w2rb, b2, h2b, part);

  // 5. attention (72 KB LDS) + ca tail blocks -> bf16 (aliases xnb), av
  attn_ca<<<1538, 256, 0, stream>>>(qbb, kbb, vbb, rpb4, attnrb,
                                    part, ca1w, ca1b, ca2w, ca2b, av);

  // 6. proj + window reverse + residual + fused LN2
  proj_ln<<<686, 256, 0, stream>>>(attnrb, projwb, projb, x, h2b, av, n2g, n2b, xo, hlnb);

  // 7. MLP
  fc1_128<<<343 * 6, 256, 0, stream>>>(hlnb, fc1wb, fc1b, hidb);
  fc2_n<<<686, 256, 0, stream>>>(hidb, fc2wb, fc2b, xo, out);
}

// Round 18
// 386.800 us; speedup vs baseline: 1.2035x; 1.1836x over previous
//
#include <hip/hip_runtime.h>
#include <math.h>

// ---------------- problem constants ----------------
constexpr int CB  = 2;
constexpr int CL  = 28 * 28 * 28;   // 21952
constexpr int CC  = 192;
constexpr int CM  = CB * CL;        // 43904 total tokens (= 128 windows * 343)

typedef unsigned short ushortT;
typedef __attribute__((ext_vector_type(8))) short bf16x8;
typedef __attribute__((ext_vector_type(4))) float f32x4;

// bijective XCD swizzle (m204)
__device__ __forceinline__ int xcd_swz(int lid, int total) {
  int q = total >> 3, r = total & 7;
  int x = lid & 7, s = lid >> 3;
  return (x < r ? x * (q + 1) : r * (q + 1) + (x - r) * q) + s;
}

__device__ __forceinline__ int tt_to_pos(int tt, int& b) {
  int bw = tt / 343;
  int n  = tt - bw * 343;
  b = bw >> 6;
  int wi = bw & 63;
  int n0 = n / 49, r = n - n0 * 49;
  int n1 = r / 7,  n2 = r - n1 * 7;
  int h = (wi >> 4) * 7 + n0;
  int w = ((wi >> 2) & 3) * 7 + n1;
  int t = (wi & 3) * 7 + n2;
  return (h * 28 + w) * 28 + t;
}

__device__ __forceinline__ float gelu_exact(float x) {
  return 0.5f * x * (1.0f + erff(x * 0.70710678118654752f));
}

__device__ __forceinline__ ushortT f2b(float x) {
  unsigned int u = __builtin_bit_cast(unsigned int, x);
  unsigned int r = (u + 0x7FFFu + ((u >> 16) & 1u)) >> 16;
  return (ushortT)r;
}
__device__ __forceinline__ float b2f(ushortT u) {
  return __builtin_bit_cast(float, (unsigned int)u << 16);
}

// async global->LDS, 16B per lane
typedef __attribute__((address_space(3))) unsigned int lds_uint;
typedef const __attribute__((address_space(1))) unsigned int glb_uint;
__device__ __forceinline__ void stage16(const ushortT* g, ushortT* l) {
#if defined(__has_builtin) && __has_builtin(__builtin_amdgcn_global_load_lds)
  __builtin_amdgcn_global_load_lds((glb_uint*)g, (lds_uint*)l, 16, 0, 0);
#else
  *(uint4*)l = *(const uint4*)g;
#endif
}

// swizzled LDS fragment pointer: 128B rows, 16B chunks, chunk ^= row&7
__device__ __forceinline__ const bf16x8* ldsfrag(const ushortT* base, int row, int chunk) {
  return (const bf16x8*)((const char*)base + row * 128 + ((chunk ^ (row & 7)) << 4));
}

// ---------------- fused: LayerNorm1 (x,y) + weight prep + rpb4 table ----------------
// blocks [0, 21952): LN rows; blocks [21952, 26998): prep elements.
__global__ __launch_bounds__(256) void ln_prep_kernel(
    const float* __restrict__ in0, const float* __restrict__ in1,
    const float* __restrict__ g, const float* __restrict__ bb,
    ushortT* __restrict__ out0, ushortT* __restrict__ out1,
    const float* __restrict__ qkvw, const float* __restrict__ projw,
    const float* __restrict__ fc1w, const float* __restrict__ fc2w,
    const float* __restrict__ w1, const float* __restrict__ w2,
    const float* __restrict__ rpb,
    ushortT* qkvwb, ushortT* projwb, ushortT* fc1wb, ushortT* fc2wb,
    ushortT* w1rb, ushortT* w2rb, float4* rpb4) {
  int bid = blockIdx.x;
  if (bid < 21952) {
    int wave = threadIdx.x >> 6;
    int lane = threadIdx.x & 63;
    const float* in = (bid & 1) ? in1 : in0;
    ushortT* out = (bid & 1) ? out1 : out0;
    int row = (bid >> 1) * 4 + wave;
    const float* p = in + (size_t)row * CC;
    float v0 = p[lane], v1 = p[lane + 64], v2 = p[lane + 128];
    float s = v0 + v1 + v2;
    for (int o = 32; o; o >>= 1) s += __shfl_xor(s, o, 64);
    float mean = s * (1.0f / 192.0f);
    float d0 = v0 - mean, d1 = v1 - mean, d2 = v2 - mean;
    float qs = d0 * d0 + d1 * d1 + d2 * d2;
    for (int o = 32; o; o >>= 1) qs += __shfl_xor(qs, o, 64);
    float rs = rsqrtf(qs * (1.0f / 192.0f) + 1e-5f);
    ushortT* po = out + (size_t)row * CC;
    po[lane]       = f2b(d0 * rs * g[lane]       + bb[lane]);
    po[lane + 64]  = f2b(d1 * rs * g[lane + 64]  + bb[lane + 64]);
    po[lane + 128] = f2b(d2 * rs * g[lane + 128] + bb[lane + 128]);
    return;
  }
  int i = (bid - 21952) * 256 + threadIdx.x;
  if (i < 110592) { qkvwb[i] = f2b(qkvw[i]); return; }
  i -= 110592;
  if (i < 36864) { projwb[i] = f2b(projw[i]); return; }
  i -= 36864;
  if (i < 147456) { fc1wb[i] = f2b(fc1w[i]); return; }
  i -= 147456;
  if (i < 147456) { fc2wb[i] = f2b(fc2w[i]); return; }
  i -= 147456;
  if (i < 331776) {
    int o = i / 5184, r = i - o * 5184, tap = r / 192, c = r - tap * 192;
    w1rb[i] = f2b(w1[o * 5184 + c * 27 + tap]); return;
  }
  i -= 331776;
  if (i < 331776) {
    int o = i / 1728, r = i - o * 1728, tap = r / 64, c = r - tap * 64;
    w2rb[i] = f2b(w2[o * 1728 + c * 27 + tap]); return;
  }
  i -= 331776;
  if (i < 6 * 88 * 352) {
    int head = i / (88 * 352);
    int rem = i - head * 88 * 352;
    int qgrp = rem / 352, k = rem - qgrp * 352;
    float4 v = make_float4(0.f, 0.f, 0.f, 0.f);
    if (k < 343) {
      int b0 = k / 49, rb = k - b0 * 49; int b1 = rb / 7, b2 = rb - b1 * 7;
#pragma unroll
      for (int r = 0; r < 4; ++r) {
        int q = qgrp * 4 + r;
        if (q < 343) {
          int a0 = q / 49, ra = q - a0 * 49; int a1 = ra / 7, a2 = ra - a1 * 7;
          int ridx = ((a0 - b0 + 6) * 13 + (a1 - b1 + 6)) * 13 + (a2 - b2 + 6);
          (&v.x)[r] = rpb[ridx * 6 + head];
        }
      }
    }
    rpb4[i] = v;
  }
}

// ======== GEMM core: BM=64, BK=64, 4 waves (2x2), SINGLE buffer ========
#define CORE_IDS \
  const int tid = threadIdx.x; \
  const int wave = tid >> 6, lane = tid & 63; \
  const int fr = lane & 15, g = lane >> 4; \
  const int wr = wave >> 1, wc = wave & 1;

#define ZERO_ACC(NF) \
  f32x4 acc[2][NF]; \
  _Pragma("unroll") \
  for (int m_ = 0; m_ < 2; ++m_) { \
    _Pragma("unroll") \
    for (int n_ = 0; n_ < NF; ++n_) acc[m_][n_] = (f32x4){0.f, 0.f, 0.f, 0.f}; \
  }

#define SETUP_A_ROWMAJOR(BASE, LDA) \
  const ushortT* pa[2]; ushortT* la[2]; \
  _Pragma("unroll") \
  for (int i = 0; i < 2; ++i) { \
    int slot = i * 256 + tid; int row_ = slot >> 3; \
    int cc8 = ((slot & 7) ^ (row_ & 7)) * 8; \
    pa[i] = (BASE) + (size_t)(blockIdx.x * 64 + row_) * (LDA) + cc8; \
    la[i] = Asl + slot * 8; \
  }

#define SETUP_A_WINDOWED(BASE) \
  const ushortT* pa[2]; ushortT* la[2]; \
  _Pragma("unroll") \
  for (int i = 0; i < 2; ++i) { \
    int slot = i * 256 + tid; int row_ = slot >> 3; \
    int cc8 = ((slot & 7) ^ (row_ & 7)) * 8; \
    int bq_; int pos_ = tt_to_pos(blockIdx.x * 64 + row_, bq_); \
    pa[i] = (BASE) + ((size_t)bq_ * CL + pos_) * CC + cc8; \
    la[i] = Asl + slot * 8; \
  }

#define SETUP_B(BASE, ROWOFF, LDB, NR) \
  const ushortT* pb[NR]; ushortT* lb[NR]; \
  _Pragma("unroll") \
  for (int i = 0; i < NR; ++i) { \
    int slot = i * 256 + tid; int row_ = slot >> 3; \
    int cc8 = ((slot & 7) ^ (row_ & 7)) * 8; \
    pb[i] = (BASE) + (size_t)((ROWOFF) + row_) * (LDB) + cc8; \
    lb[i] = Bsl + slot * 8; \
  }

#define STAGE_AB(NR) \
  _Pragma("unroll") \
  for (int i = 0; i < 2; ++i) { stage16(pa[i], la[i]); pa[i] += 64; } \
  _Pragma("unroll") \
  for (int i = 0; i < NR; ++i) { stage16(pb[i], lb[i]); pb[i] += 64; }

#define CORE_MFMA(NF) \
  __syncthreads(); \
  _Pragma("unroll") \
  for (int kk = 0; kk < 2; ++kk) { \
    bf16x8 a0 = *ldsfrag(Asl, wr * 32 + fr, kk * 4 + g); \
    bf16x8 a1 = *ldsfrag(Asl, wr * 32 + 16 + fr, kk * 4 + g); \
    _Pragma("unroll") \
    for (int n_ = 0; n_ < NF; ++n_) { \
      bf16x8 bn = *ldsfrag(Bsl, wc * ((NF) * 16) + n_ * 16 + fr, kk * 4 + g); \
      acc[0][n_] = __builtin_amdgcn_mfma_f32_16x16x32_bf16(a0, bn, acc[0][n_], 0, 0, 0); \
      acc[1][n_] = __builtin_amdgcn_mfma_f32_16x16x32_bf16(a1, bn, acc[1][n_], 0, 0, 0); \
    } \
  } \
  __syncthreads();

// ======== 128x128 core, SINGLE buffer; M-block index from local var `mblk` ========
#define M128_ZERO \
  f32x4 acc[4][4]; \
  _Pragma("unroll") \
  for (int m_ = 0; m_ < 4; ++m_) \
    _Pragma("unroll") \
    for (int n_ = 0; n_ < 4; ++n_) acc[m_][n_] = (f32x4){0.f, 0.f, 0.f, 0.f};

#define M128_SETUP_A_ROWMAJOR(BASE, LDA) \
  const ushortT* pa[4]; ushortT* la[4]; \
  _Pragma("unroll") \
  for (int i = 0; i < 4; ++i) { \
    int slot = i * 256 + tid; int row_ = slot >> 3; \
    int cc8 = ((slot & 7) ^ (row_ & 7)) * 8; \
    pa[i] = (BASE) + (size_t)(mblk * 128 + row_) * (LDA) + cc8; \
    la[i] = Asl + slot * 8; \
  }

#define M128_SETUP_A_WINDOWED(BASE) \
  const ushortT* pa[4]; ushortT* la[4]; \
  _Pragma("unroll") \
  for (int i = 0; i < 4; ++i) { \
    int slot = i * 256 + tid; int row_ = slot >> 3; \
    int cc8 = ((slot & 7) ^ (row_ & 7)) * 8; \
    int bq_; int pos_ = tt_to_pos(mblk * 128 + row_, bq_); \
    pa[i] = (BASE) + ((size_t)bq_ * CL + pos_) * CC + cc8; \
    la[i] = Asl + slot * 8; \
  }

#define M128_SETUP_B(BASE, ROWOFF, LDB) \
  const ushortT* pb[4]; ushortT* lb[4]; \
  _Pragma("unroll") \
  for (int i = 0; i < 4; ++i) { \
    int slot = i * 256 + tid; int row_ = slot >> 3; \
    int cc8 = ((slot & 7) ^ (row_ & 7)) * 8; \
    pb[i] = (BASE) + (size_t)((ROWOFF) + row_) * (LDB) + cc8; \
    lb[i] = Bsl + slot * 8; \
  }

#define M128_STAGE \
  { _Pragma("unroll") \
    for (int i = 0; i < 4; ++i) { stage16(pa[i], la[i]); pa[i] += 64; } \
    _Pragma("unroll") \
    for (int i = 0; i < 4; ++i) { stage16(pb[i], lb[i]); pb[i] += 64; } }

#define M128_MFMA \
  { _Pragma("unroll") \
    for (int kk = 0; kk < 2; ++kk) { \
      bf16x8 am[4], bn[4]; \
      _Pragma("unroll") \
      for (int m_ = 0; m_ < 4; ++m_) am[m_] = *ldsfrag(Asl, wr * 64 + m_ * 16 + fr, kk * 4 + g); \
      _Pragma("unroll") \
      for (int n_ = 0; n_ < 4; ++n_) bn[n_] = *ldsfrag(Bsl, wc * 64 + n_ * 16 + fr, kk * 4 + g); \
      _Pragma("unroll") \
      for (int m_ = 0; m_ < 4; ++m_) \
        _Pragma("unroll") \
        for (int n_ = 0; n_ < 4; ++n_) \
          acc[m_][n_] = __builtin_amdgcn_mfma_f32_16x16x32_bf16(am[m_], bn[n_], acc[m_][n_], 0, 0, 0); \
    } }

#define M128_LOOP(KS) \
  _Pragma("unroll") \
  for (int ks = 0; ks < (KS); ++ks) { \
    M128_STAGE \
    __syncthreads(); \
    M128_MFMA \
    __syncthreads(); \
  }

// ---------------- Q projection -> bf16 [wh][n][32], scaled ----------------
__global__ __launch_bounds__(256) void gemm_q_n(const ushortT* __restrict__ xnb,
                                                const ushortT* __restrict__ qkvwb,
                                                const float* __restrict__ qkvb,
                                                ushortT* __restrict__ qout) {
  __shared__ alignas(16) ushortT Asl[64 * 64];
  __shared__ alignas(16) ushortT Bsl[192 * 64];
  CORE_IDS
  ZERO_ACC(6)
  SETUP_A_WINDOWED(xnb)
  SETUP_B(qkvwb, 0, 192, 6)
  for (int ks = 0; ks < 3; ++ks) {
    STAGE_AB(6)
    CORE_MFMA(6)
  }
#pragma unroll
  for (int n = 0; n < 6; ++n) {
    int jj = wc * 96 + n * 16 + fr;
    int head = jj >> 5, d = jj & 31;
    float bias = qkvb[jj];
#pragma unroll
    for (int m = 0; m < 2; ++m)
#pragma unroll
      for (int r = 0; r < 4; ++r) {
        int tt = blockIdx.x * 64 + wr * 32 + m * 16 + g * 4 + r;
        int bw = tt / 343, nn = tt - bw * 343;
        qout[(((size_t)bw * 6 + head) * 343 + nn) * 32 + d] =
            f2b((acc[m][n][r] + bias) * 0.17677669529663687f);
      }
  }
}

// ---------------- K,V projection (128x128 core, XCD-swizzled) ----------------
__global__ __launch_bounds__(256) void kv_128(const ushortT* __restrict__ ynb,
                                              const ushortT* __restrict__ qkvwb,
                                              const float* __restrict__ qkvb,
                                              ushortT* __restrict__ kout,
                                              ushortT* __restrict__ vout) {
  __shared__ alignas(16) ushortT Asl[8192];
  __shared__ alignas(16) ushortT Bsl[8192];
  CORE_IDS
  const int wid = xcd_swz(blockIdx.x, 343 * 3);
  const int mblk = wid / 3;
  const int jb = (wid - mblk * 3) * 128;
  M128_ZERO
  M128_SETUP_A_WINDOWED(ynb)
  M128_SETUP_B(qkvwb, 192 + jb, 192)
  M128_LOOP(3)
#pragma unroll
  for (int ni = 0; ni < 4; ++ni) {
    int jj = jb + wc * 64 + ni * 16 + fr;       // 0..383
    float bias = qkvb[192 + jj];
#pragma unroll
    for (int mi = 0; mi < 4; ++mi)
#pragma unroll
      for (int r = 0; r < 4; ++r) {
        int tt = mblk * 128 + wr * 64 + mi * 16 + g * 4 + r;
        int bw = tt / 343, nn = tt - bw * 343;
        float val = acc[mi][ni][r] + bias;
        if (jj < 192) {
          int head = jj >> 5, d = jj & 31;
          kout[(((size_t)bw * 6 + head) * 343 + nn) * 32 + d] = f2b(val);
        } else {
          int jv = jj - 192;
          int head = jv >> 5, d = jv & 31;
          vout[((size_t)bw * 6 + head) * 11264 + (size_t)d * 352 + nn] = f2b(val);
        }
      }
  }
}

// ---------------- conv core: BM=128, BN=64, single buffer, reg-prefetch A, XCD-swizzled ----------------
// MODE 2: split-K bf16 partial (conv1). MODE 0: N-split bf16+bias (conv2) + pooled sums.
template <int CIN, int COUTT, int MODE>
__global__ __launch_bounds__(256) void conv128(const ushortT* __restrict__ src,
                                               const ushortT* __restrict__ wrw,
                                               const float* __restrict__ bias,
                                               void* __restrict__ dst,
                                               float* __restrict__ part) {
  constexpr int KT = 27 * CIN;
  constexpr int KN = KT / 64;
  constexpr int NY = (MODE == 2) ? 4 : (COUTT / 64);
  constexpr int NBLK = 343 * NY;
  __shared__ alignas(16) ushortT Asl[8192];   // 16 KB
  __shared__ alignas(16) ushortT Bsl[4096];   // 8 KB
  const int tid = threadIdx.x;
  const int wave = tid >> 6, lane = tid & 63;
  const int fr = lane & 15, g = lane >> 4;
  const int wid = xcd_swz(blockIdx.x, NBLK);
  const int mblk = wid / NY;
  const int ysub = wid - mblk * NY;
  f32x4 acc[2][4];
#pragma unroll
  for (int m = 0; m < 2; ++m)
#pragma unroll
    for (int n = 0; n < 4; ++n) acc[m][n] = (f32x4){0.f, 0.f, 0.f, 0.f};

  const int kb = (MODE == 2) ? (ysub * KN) / 4 : 0;
  const int ke = (MODE == 2) ? ((ysub + 1) * KN) / 4 : KN;
  const int jbN = (MODE == 0) ? ysub * 64 : 0;

  const ushortT* srcb[4];
  ushortT* la[4];
  unsigned vmask[4];
#pragma unroll
  for (int i = 0; i < 4; ++i) {
    int slot = i * 256 + tid; int row_ = slot >> 3;
    int cc8 = ((slot & 7) ^ (row_ & 7)) * 8;
    int grow = mblk * 128 + row_;
    int bbq = grow / CL;
    int pos = grow - bbq * CL;
    int h = pos / 784, w = (pos / 28) % 28, t = pos % 28;
    unsigned vm = 0;
#pragma unroll
    for (int tap = 0; tap < 27; ++tap) {
      int dh = tap / 9 - 1, dw = (tap / 3) % 3 - 1, dt = tap % 3 - 1;
      bool ok = ((unsigned)(h + dh) < 28u) && ((unsigned)(w + dw) < 28u) &&
                ((unsigned)(t + dt) < 28u);
      vm |= (unsigned)ok << tap;
    }
    vmask[i] = vm;
    srcb[i] = src + ((size_t)bbq * CL + pos) * CIN + cc8;
    la[i] = Asl + slot * 8;
  }
  const ushortT* pb[2]; ushortT* lb[2];
#pragma unroll
  for (int i = 0; i < 2; ++i) {
    int slot = i * 256 + tid; int row_ = slot >> 3;
    int cc8 = ((slot & 7) ^ (row_ & 7)) * 8;
    pb[i] = wrw + (size_t)(jbN + row_) * KT + kb * 64 + cc8;
    lb[i] = Bsl + slot * 8;
  }

  auto loadA = [&](int ks, int i) -> uint4 {
    int tap, cb;
    if (CIN == 64) { tap = ks; cb = 0; }
    else           { tap = ks / 3; cb = (ks - tap * 3) * 64; }
    int off = ((tap / 9 - 1) * 784 + ((tap / 3) % 3 - 1) * 28 + (tap % 3 - 1)) * CIN + cb;
    uint4 v = make_uint4(0u, 0u, 0u, 0u);
    if ((vmask[i] >> tap) & 1u) v = *(const uint4*)(srcb[i] + off);
    return v;
  };

  uint4 vr[4];
#pragma unroll
  for (int i = 0; i < 4; ++i) vr[i] = loadA(kb, i);
  for (int ks = kb; ks < ke; ++ks) {
#pragma unroll
    for (int i = 0; i < 4; ++i) *(uint4*)la[i] = vr[i];
#pragma unroll
    for (int i = 0; i < 2; ++i) { stage16(pb[i], lb[i]); pb[i] += 64; }
    __syncthreads();
    bool more = (ks + 1 < ke);
    if (more) {
#pragma unroll
      for (int i = 0; i < 4; ++i) vr[i] = loadA(ks + 1, i);
    }
#pragma unroll
    for (int kk = 0; kk < 2; ++kk) {
      bf16x8 a0 = *ldsfrag(Asl, wave * 32 + fr, kk * 4 + g);
      bf16x8 a1 = *ldsfrag(Asl, wave * 32 + 16 + fr, kk * 4 + g);
#pragma unroll
      for (int n = 0; n < 4; ++n) {
        bf16x8 bn = *ldsfrag(Bsl, n * 16 + fr, kk * 4 + g);
        acc[0][n] = __builtin_amdgcn_mfma_f32_16x16x32_bf16(a0, bn, acc[0][n], 0, 0, 0);
        acc[1][n] = __builtin_amdgcn_mfma_f32_16x16x32_bf16(a1, bn, acc[1][n], 0, 0, 0);
      }
    }
    __syncthreads();
  }
  if (MODE == 2) {
    // bf16 partials (half the traffic of fp32; error ~1e-3 << threshold)
#pragma unroll
    for (int n = 0; n < 4; ++n) {
      int jj = n * 16 + fr;
#pragma unroll
      for (int m = 0; m < 2; ++m)
#pragma unroll
        for (int r = 0; r < 4; ++r) {
          int grow = mblk * 128 + wave * 32 + m * 16 + g * 4 + r;
          ((ushortT*)dst)[((size_t)ysub * CM + grow) * 64 + jj] = f2b(acc[m][n][r]);
        }
    }
  } else {
    // conv2 epilogue: bf16 store + fused spatial-pool partial sums
    float* red = (float*)Asl;   // 512 floats (Asl dead, post-barrier)
#pragma unroll
    for (int n = 0; n < 4; ++n) {
      int jj = n * 16 + fr;
      float bs = bias[jbN + jj];
      float s0 = 0.f, s1 = 0.f;
#pragma unroll
      for (int m = 0; m < 2; ++m)
#pragma unroll
        for (int r = 0; r < 4; ++r) {
          int grow = mblk * 128 + wave * 32 + m * 16 + g * 4 + r;
          float v = acc[m][n][r] + bs;
          ((ushortT*)dst)[(size_t)grow * COUTT + jbN + jj] = f2b(v);
          if (grow < CL) s0 += v; else s1 += v;
        }
      s0 += __shfl_xor(s0, 16, 64); s0 += __shfl_xor(s0, 32, 64);
      s1 += __shfl_xor(s1, 16, 64); s1 += __shfl_xor(s1, 32, 64);
      if (g == 0) {
        red[((wave * 4 + n) * 16 + fr) * 2 + 0] = s0;
        red[((wave * 4 + n) * 16 + fr) * 2 + 1] = s1;
      }
    }
    __syncthreads();
    if (tid < 128) {
      int chl = tid >> 1, bsel = tid & 1;       // chl in [0,64)
      float s = 0.f;
#pragma unroll
      for (int wv = 0; wv < 4; ++wv)
        s += red[((wv * 4 + (chl >> 4)) * 16 + (chl & 15)) * 2 + bsel];
      if (s != 0.0f) atomicAdd(&part[bsel * 192 + jbN + chl], s);
    }
  }
}

// ---------------- conv1 combine: 4 bf16 partials + bias -> GELU -> bf16 ----------------
__global__ __launch_bounds__(256) void comb1_kernel(const ushortT* __restrict__ pc,
                                                    const float* __restrict__ b1,
                                                    ushortT* __restrict__ h1b) {
  size_t idx = ((size_t)blockIdx.x * 256 + threadIdx.x) * 4;
  ushort4 a = *(const ushort4*)(pc + idx);
  ushort4 b = *(const ushort4*)(pc + (size_t)CM * 64 + idx);
  ushort4 c = *(const ushort4*)(pc + (size_t)CM * 128 + idx);
  ushort4 d = *(const ushort4*)(pc + (size_t)CM * 192 + idx);
  int c0 = (int)(idx & 63);
  ushortT o0 = f2b(gelu_exact(b2f(a.x) + b2f(b.x) + b2f(c.x) + b2f(d.x) + b1[c0 + 0]));
  ushortT o1 = f2b(gelu_exact(b2f(a.y) + b2f(b.y) + b2f(c.y) + b2f(d.y) + b1[c0 + 1]));
  ushortT o2 = f2b(gelu_exact(b2f(a.z) + b2f(b.z) + b2f(c.z) + b2f(d.z) + b1[c0 + 2]));
  ushortT o3 = f2b(gelu_exact(b2f(a.w) + b2f(b.w) + b2f(c.w) + b2f(d.w) + b1[c0 + 3]));
  unsigned int w0 = (unsigned int)o0 | ((unsigned int)o1 << 16);
  unsigned int w1 = (unsigned int)o2 | ((unsigned int)o3 << 16);
  *(uint2*)&h1b[idx] = make_uint2(w0, w1);
}

// ---------------- MFMA fused window attention (direct __shared__) + ca tail blocks ----------------
constexpr int KP  = 36;
constexpr int VP  = 356;
constexpr int VP2 = 200;

__global__ __launch_bounds__(256) void attn_ca(const ushortT* __restrict__ qb,
                                               const ushortT* __restrict__ kb,
                                               const ushortT* __restrict__ vb,
                                               const float* __restrict__ rpb4,
                                               ushortT* __restrict__ aout,
                                               const float* __restrict__ part,
                                               const float* __restrict__ ca1w,
                                               const float* __restrict__ ca1b,
                                               const float* __restrict__ ca2w,
                                               const float* __restrict__ ca2b,
                                               float* __restrict__ av) {
  __shared__ ushortT Kl[352 * KP];
  __shared__ ushortT Vt[32 * VP];
  __shared__ ushortT Pl[64 * VP2];
  const int tid = threadIdx.x;

  if (blockIdx.x >= 1536) {
    // channel-attention block (b = 0/1); uniform barriers, tid-guarded work
    int b = blockIdx.x - 1536;
    float* pl = (float*)Kl;
    float* hid = pl + 192;
    if (tid < 192) pl[tid] = part[b * 192 + tid] * (1.0f / (float)CL);
    __syncthreads();
    if (tid < 12) {
      float t = ca1b[tid];
      for (int i = 0; i < 192; ++i) t += ca1w[tid * 192 + i] * pl[i];
      hid[tid] = fmaxf(t, 0.0f);
    }
    __syncthreads();
    if (tid < 192) {
      float t = ca2b[tid];
#pragma unroll
      for (int j = 0; j < 12; ++j) t += ca2w[tid * 12 + j] * hid[j];
      av[b * 192 + tid] = 1.0f / (1.0f + __expf(-t));
    }
    return;
  }

  const int wave = tid >> 6, lane = tid & 63;
  const int fr = lane & 15, g = lane >> 4, fk = g * 8;
  const int wid = xcd_swz(blockIdx.x, 768 * 2);
  const int wh = wid >> 1;
  const int qhalf = wid & 1;
  const int bw = wh / 6, head = wh - bw * 6;
  const ushortT* kp = kb + (size_t)wh * 343 * 32;
  const ushortT* vp = vb + (size_t)wh * 11264;
  const ushortT* qp = qb + (size_t)wh * 343 * 32;
  const f32x4* bp4 = (const f32x4*)rpb4 + (size_t)head * 88 * 352;

  for (int c = tid; c < 1372; c += 256) {
    int key = c >> 2, part_ = c & 3;
    *(uint4*)&Kl[key * KP + part_ * 8] = *(const uint4*)(kp + (size_t)c * 8);
  }
  for (int c = tid; c < 1408; c += 256) {
    int d = c / 44, p = c - d * 44;
    *(uint4*)&Vt[d * VP + p * 8] = *(const uint4*)(vp + (size_t)c * 8);
  }
  __syncthreads();  // staging visible

  for (int qi = 0; qi < 3; ++qi) {
    const int q0 = (qhalf * 3 + qi) * 64;

    int qrow = q0 + wave * 16 + fr; if (qrow > 342) qrow = 342;
    bf16x8 aq = *(const bf16x8*)(qp + (size_t)qrow * 32 + fk);

    const int qgrp = (q0 + wave * 16) / 4 + g;
    f32x4 sc[22];
#pragma unroll
    for (int t = 0; t < 22; ++t) {
      f32x4 cini = bp4[(size_t)qgrp * 352 + t * 16 + fr];
      bf16x8 bk = *(const bf16x8*)&Kl[(t * 16 + fr) * KP + fk];
      sc[t] = __builtin_amdgcn_mfma_f32_16x16x32_bf16(aq, bk, cini, 0, 0, 0);
    }
    if (fr > 6) { sc[21][0] = -1e30f; sc[21][1] = -1e30f; sc[21][2] = -1e30f; sc[21][3] = -1e30f; }

    // softmax without max-subtract: |s| <= O(1), exp exact; pad exp(-1e30) -> 0
    float rinv[4];
#pragma unroll
    for (int r = 0; r < 4; ++r) {
      float sum = 0.0f;
#pragma unroll
      for (int t = 0; t < 22; ++t) {
        float e = __expf(sc[t][r]);
        sc[t][r] = e;
        sum += e;
      }
      sum += __shfl_xor(sum, 1, 64); sum += __shfl_xor(sum, 2, 64);
      sum += __shfl_xor(sum, 4, 64); sum += __shfl_xor(sum, 8, 64);
      rinv[r] = 1.0f / sum;
    }

    f32x4 o0 = {0.f, 0.f, 0.f, 0.f}, o1 = {0.f, 0.f, 0.f, 0.f};

#pragma unroll
    for (int t = 0; t < 12; ++t)
#pragma unroll
      for (int r = 0; r < 4; ++r)
        Pl[(wave * 16 + g * 4 + r) * VP2 + t * 16 + fr] = f2b(sc[t][r]);
    asm volatile("s_waitcnt lgkmcnt(0)" ::: "memory");
#pragma unroll
    for (int s = 0; s < 6; ++s) {
      bf16x8 ap  = *(const bf16x8*)&Pl[(wave * 16 + fr) * VP2 + s * 32 + fk];
      bf16x8 bv0 = *(const bf16x8*)&Vt[fr * VP + s * 32 + fk];
      bf16x8 bv1 = *(const bf16x8*)&Vt[(16 + fr) * VP + s * 32 + fk];
      o0 = __builtin_amdgcn_mfma_f32_16x16x32_bf16(ap, bv0, o0, 0, 0, 0);
      o1 = __builtin_amdgcn_mfma_f32_16x16x32_bf16(ap, bv1, o1, 0, 0, 0);
    }
    asm volatile("s_waitcnt lgkmcnt(0)" ::: "memory");

#pragma unroll
    for (int t = 12; t < 22; ++t)
#pragma unroll
      for (int r = 0; r < 4; ++r)
        Pl[(wave * 16 + g * 4 + r) * VP2 + (t - 12) * 16 + fr] = f2b(sc[t][r]);
    asm volatile("s_waitcnt lgkmcnt(0)" ::: "memory");
#pragma unroll
    for (int s = 0; s < 5; ++s) {
      bf16x8 ap  = *(const bf16x8*)&Pl[(wave * 16 + fr) * VP2 + s * 32 + fk];
      bf16x8 bv0 = *(const bf16x8*)&Vt[fr * VP + 192 + s * 32 + fk];
      bf16x8 bv1 = *(const bf16x8*)&Vt[(16 + fr) * VP + 192 + s * 32 + fk];
      o0 = __builtin_amdgcn_mfma_f32_16x16x32_bf16(ap, bv0, o0, 0, 0, 0);
      o1 = __builtin_amdgcn_mfma_f32_16x16x32_bf16(ap, bv1, o1, 0, 0, 0);
    }
    asm volatile("s_waitcnt lgkmcnt(0)" ::: "memory");

#pragma unroll
    for (int r = 0; r < 4; ++r) {
      int q = q0 + wave * 16 + g * 4 + r;
      if (q < 343) {
        float ri = rinv[r];
        size_t base = ((size_t)bw * 343 + q) * 192 + head * 32;
        aout[base + fr]      = f2b(o0[r] * ri);
        aout[base + 16 + fr] = f2b(o1[r] * ri);
      }
    }
  }
}

// ---------------- proj + window-reverse + residual + FUSED LayerNorm2 ----------------
__global__ __launch_bounds__(256) void proj_ln(const ushortT* __restrict__ attnrb,
                                               const ushortT* __restrict__ projwb,
                                               const float* __restrict__ projb,
                                               const float* __restrict__ x0,
                                               const ushortT* __restrict__ h2b,
                                               const float* __restrict__ cav,
                                               const float* __restrict__ n2g,
                                               const float* __restrict__ n2b,
                                               float* __restrict__ xout,
                                               ushortT* __restrict__ hlnb) {
  __shared__ alignas(16) ushortT Asl[64 * 64];
  __shared__ alignas(16) ushortT Bsl[192 * 64];
  CORE_IDS
  ZERO_ACC(6)
  SETUP_A_ROWMAJOR(attnrb, CC)
  SETUP_B(projwb, 0, 192, 6)
  for (int ks = 0; ks < 3; ++ks) {
    STAGE_AB(6)
    CORE_MFMA(6)
  }
  // residual: acc <- x0 + acc + projb + h2*cav; write xout (spatial)
  size_t sbase[2][4];
#pragma unroll
  for (int m = 0; m < 2; ++m)
#pragma unroll
    for (int r = 0; r < 4; ++r) {
      int tt = blockIdx.x * 64 + wr * 32 + m * 16 + g * 4 + r;
      int bq_;
      int pos_ = tt_to_pos(tt, bq_);
      size_t base = ((size_t)bq_ * CL + pos_) * CC;
      sbase[m][r] = base;
#pragma unroll
      for (int n = 0; n < 6; ++n) {
        int jj = wc * 96 + n * 16 + fr;
        size_t addr = base + jj;
        float v = x0[addr] + acc[m][n][r] + projb[jj] + b2f(h2b[addr]) * cav[bq_ * 192 + jj];
        acc[m][n][r] = v;
        xout[addr] = v;
      }
    }
  // fused LN2: per-row stats via shfl + cross-wc LDS exchange
  float* stats = (float*)Asl;
#pragma unroll
  for (int m = 0; m < 2; ++m)
#pragma unroll
    for (int r = 0; r < 4; ++r) {
      float ps = 0.f, ps2 = 0.f;
#pragma unroll
      for (int n = 0; n < 6; ++n) { float v = acc[m][n][r]; ps += v; ps2 += v * v; }
      ps  += __shfl_xor(ps, 1, 64);  ps2 += __shfl_xor(ps2, 1, 64);
      ps  += __shfl_xor(ps, 2, 64);  ps2 += __shfl_xor(ps2, 2, 64);
      ps  += __shfl_xor(ps, 4, 64);  ps2 += __shfl_xor(ps2, 4, 64);
      ps  += __shfl_xor(ps, 8, 64);  ps2 += __shfl_xor(ps2, 8, 64);
      if (fr == 0) {
        int lrow = wr * 32 + m * 16 + g * 4 + r;
        stats[lrow * 4 + wc * 2]     = ps;
        stats[lrow * 4 + wc * 2 + 1] = ps2;
      }
    }
  __syncthreads();
#pragma unroll
  for (int m = 0; m < 2; ++m)
#pragma unroll
    for (int r = 0; r < 4; ++r) {
      int lrow = wr * 32 + m * 16 + g * 4 + r;
      float s  = stats[lrow * 4]     + stats[lrow * 4 + 2];
      float s2 = stats[lrow * 4 + 1] + stats[lrow * 4 + 3];
      float mean = s * (1.0f / 192.0f);
      float var  = s2 * (1.0f / 192.0f) - mean * mean;
      float rs = rsqrtf(var + 1e-5f);
      ushortT* po = hlnb + sbase[m][r];   // spatial row
#pragma unroll
      for (int n = 0; n < 6; ++n) {
        int jj = wc * 96 + n * 16 + fr;
        po[jj] = f2b((acc[m][n][r] - mean) * rs * n2g[jj] + n2b[jj]);
      }
    }
}

// ---------------- MLP fc1 (128x128 core, XCD-swizzled) ----------------
__global__ __launch_bounds__(256) void fc1_128(const ushortT* __restrict__ hlnb,
                                               const ushortT* __restrict__ fc1wb,
                                               const float* __restrict__ fc1b,
                                               ushortT* __restrict__ hidb) {
  __shared__ alignas(16) ushortT Asl[8192];
  __shared__ alignas(16) ushortT Bsl[8192];
  CORE_IDS
  const int wid = xcd_swz(blockIdx.x, 343 * 6);
  const int mblk = wid / 6;
  const int jb = (wid - mblk * 6) * 128;
  M128_ZERO
  M128_SETUP_A_ROWMAJOR(hlnb, CC)
  M128_SETUP_B(fc1wb, jb, 192)
  M128_LOOP(3)
#pragma unroll
  for (int ni = 0; ni < 4; ++ni) {
    int jj = jb + wc * 64 + ni * 16 + fr;
    float bs = fc1b[jj];
#pragma unroll
    for (int mi = 0; mi < 4; ++mi)
#pragma unroll
      for (int r = 0; r < 4; ++r) {
        int grow = mblk * 128 + wr * 64 + mi * 16 + g * 4 + r;
        hidb[(size_t)grow * 768 + jj] = f2b(gelu_exact(acc[mi][ni][r] + bs));
      }
  }
}

// ---------------- MLP fc2 + final residual -> d_out ----------------
__global__ __launch_bounds__(256) void fc2_n(const ushortT* __restrict__ hidb,
                                             const ushortT* __restrict__ fc2wb,
                                             const float* __restrict__ fc2b,
                                             const float* __restrict__ xout,
                                             float* __restrict__ out) {
  __shared__ alignas(16) ushortT Asl[64 * 64];
  __shared__ alignas(16) ushortT Bsl[192 * 64];
  CORE_IDS
  ZERO_ACC(6)
  SETUP_A_ROWMAJOR(hidb, 768)
  SETUP_B(fc2wb, 0, 768, 6)
  for (int ks = 0; ks < 12; ++ks) {
    STAGE_AB(6)
    CORE_MFMA(6)
  }
#pragma unroll
  for (int n = 0; n < 6; ++n) {
    int jj = wc * 96 + n * 16 + fr;
    float bs = fc2b[jj];
#pragma unroll
    for (int m = 0; m < 2; ++m)
#pragma unroll
      for (int r = 0; r < 4; ++r) {
        int grow = blockIdx.x * 64 + wr * 32 + m * 16 + g * 4 + r;
        size_t addr = (size_t)grow * CC + jj;
        out[addr] = xout[addr] + acc[m][n][r] + bs;
      }
  }
}

// ---------------- launch ----------------
extern "C" void kernel_launch(void* const* d_in, const int* in_sizes, int n_in,
                              void* d_out, int out_size, void* d_ws, size_t ws_size,
                              hipStream_t stream) {
  const float* x     = (const float*)d_in[0];
  const float* y     = (const float*)d_in[1];
  const float* n1g   = (const float*)d_in[3];
  const float* n1b   = (const float*)d_in[4];
  const float* qkvw  = (const float*)d_in[5];
  const float* qkvb  = (const float*)d_in[6];
  const float* projw = (const float*)d_in[7];
  const float* projb = (const float*)d_in[8];
  const float* rpb   = (const float*)d_in[9];
  const float* n2g   = (const float*)d_in[10];
  const float* n2b   = (const float*)d_in[11];
  const float* fc1w  = (const float*)d_in[12];
  const float* fc1b  = (const float*)d_in[13];
  const float* fc2w  = (const float*)d_in[14];
  const float* fc2b  = (const float*)d_in[15];
  const float* w1    = (const float*)d_in[16];
  const float* b1    = (const float*)d_in[17];
  const float* w2    = (const float*)d_in[18];
  const float* b2    = (const float*)d_in[19];
  const float* ca1w  = (const float*)d_in[20];
  const float* ca1b  = (const float*)d_in[21];
  const float* ca2w  = (const float*)d_in[22];
  const float* ca2b  = (const float*)d_in[23];

  char* W = (char*)d_ws;
  float* out = (float*)d_out;

  ushortT* xnb  = (ushortT*)(W + 0);
  ushortT* ynb  = (ushortT*)(W + 16859136);
  ushortT* qbb  = (ushortT*)(W + 33718272);
  ushortT* kbb  = (ushortT*)(W + 50577408);
  ushortT* vbb  = (ushortT*)(W + 67436544);   // [wh][32][352] bf16
  ushortT* h1b  = (ushortT*)(W + 84738048);
  ushortT* h2b  = (ushortT*)(W + 90357760);   // bf16 (16.9 MB)
  float*   xo   = (float*)(W + 124076032);
  char*    SM   = W + 157794304;
  ushortT* qkvwb  = (ushortT*)(SM);
  ushortT* projwb = (ushortT*)(SM + 221184);
  ushortT* fc1wb  = (ushortT*)(SM + 294912);
  ushortT* fc2wb  = (ushortT*)(SM + 589824);
  ushortT* w1rb   = (ushortT*)(SM + 884736);
  ushortT* w2rb   = (ushortT*)(SM + 1548288);
  float*   rpb4   = (float*)(SM + 2211840);   // 2,973,696 B
  float*   av     = (float*)(SM + 5185536);   // 384 floats
  float*   part   = (float*)(SM + 5187072);   // 384 floats (pooled sums)
  ushortT* pc1    = (ushortT*)(SM + 5319168); // 4*CM*64 bf16 = 22,478,848 B
  ushortT* attnrb = xnb;
  ushortT* hlnb   = ynb;
  ushortT* hidb   = (ushortT*)(W + 33718272);

  // 0. zero pooled-sum accumulator (graph-capturable)
  hipMemsetAsync(part, 0, 2 * 192 * sizeof(float), stream);

  // 1. fused LN1(x,y) + weight prep + rpb4 table
  ln_prep_kernel<<<21952 + 5046, 256, 0, stream>>>(
      x, y, n1g, n1b, xnb, ynb,
      qkvw, projw, fc1w, fc2w, w1, w2, rpb,
      qkvwb, projwb, fc1wb, fc2wb, w1rb, w2rb, (float4*)rpb4);

  // 2. QKV projections
  gemm_q_n<<<686, 256, 0, stream>>>(xnb, qkvwb, qkvb, qbb);
  kv_128<<<343 * 3, 256, 0, stream>>>(ynb, qkvwb, qkvb, kbb, vbb);

  // 3. CAB convs: conv1 K-split 4 (bf16 partials) -> combine -> conv2 (bf16 + fused pool)
  conv128<192, 64, 2><<<343 * 4, 256, 0, stream>>>(xnb, w1rb, b1, pc1, nullptr);
  comb1_kernel<<<2744, 256, 0, stream>>>(pc1, b1, h1b);
  conv128<64, 192, 0><<<343 * 3, 256, 0, stream>>>(h1b, w2rb, b2, h2b, part);

  // 4. attention (+ channel-attention tail blocks) -> bf16 (aliases xnb)
  attn_ca<<<1538, 256, 0, stream>>>(qbb, kbb, vbb, rpb4, attnrb,
                                    part, ca1w, ca1b, ca2w, ca2b, av);

  // 5. proj + window reverse + residual + fused LN2 (writes xo and hlnb)
  proj_ln<<<686, 256, 0, stream>>>(attnrb, projwb, projb, x, h2b, av, n2g, n2b, xo, hlnb);

  // 6. MLP
  fc1_128<<<343 * 6, 256, 0, stream>>>(hlnb, fc1wb, fc1b, hidb);
  fc2_n<<<686, 256, 0, stream>>>(hidb, fc2wb, fc2b, xo, out);
}

// Round 19
// 369.271 us; speedup vs baseline: 1.2607x; 1.0475x over previous
//
#include <hip/hip_runtime.h>
#include <math.h>

// ---------------- problem constants ----------------
constexpr int CB  = 2;
constexpr int CL  = 28 * 28 * 28;   // 21952
constexpr int CC  = 192;
constexpr int CM  = CB * CL;        // 43904 total tokens (= 128 windows * 343)

typedef unsigned short ushortT;
typedef __attribute__((ext_vector_type(8))) short bf16x8;
typedef __attribute__((ext_vector_type(4))) float f32x4;

// bijective XCD swizzle (m204)
__device__ __forceinline__ int xcd_swz(int lid, int total) {
  int q = total >> 3, r = total & 7;
  int x = lid & 7, s = lid >> 3;
  return (x < r ? x * (q + 1) : r * (q + 1) + (x - r) * q) + s;
}

__device__ __forceinline__ int tt_to_pos(int tt, int& b) {
  int bw = tt / 343;
  int n  = tt - bw * 343;
  b = bw >> 6;
  int wi = bw & 63;
  int n0 = n / 49, r = n - n0 * 49;
  int n1 = r / 7,  n2 = r - n1 * 7;
  int h = (wi >> 4) * 7 + n0;
  int w = ((wi >> 2) & 3) * 7 + n1;
  int t = (wi & 3) * 7 + n2;
  return (h * 28 + w) * 28 + t;
}

__device__ __forceinline__ float gelu_exact(float x) {
  return 0.5f * x * (1.0f + erff(x * 0.70710678118654752f));
}

__device__ __forceinline__ ushortT f2b(float x) {
  unsigned int u = __builtin_bit_cast(unsigned int, x);
  unsigned int r = (u + 0x7FFFu + ((u >> 16) & 1u)) >> 16;
  return (ushortT)r;
}
__device__ __forceinline__ float b2f(ushortT u) {
  return __builtin_bit_cast(float, (unsigned int)u << 16);
}

// async global->LDS, 16B per lane
typedef __attribute__((address_space(3))) unsigned int lds_uint;
typedef const __attribute__((address_space(1))) unsigned int glb_uint;
__device__ __forceinline__ void stage16(const ushortT* g, ushortT* l) {
#if defined(__has_builtin) && __has_builtin(__builtin_amdgcn_global_load_lds)
  __builtin_amdgcn_global_load_lds((glb_uint*)g, (lds_uint*)l, 16, 0, 0);
#else
  *(uint4*)l = *(const uint4*)g;
#endif
}

// swizzled LDS fragment pointer: 128B rows, 16B chunks, chunk ^= row&7
__device__ __forceinline__ const bf16x8* ldsfrag(const ushortT* base, int row, int chunk) {
  return (const bf16x8*)((const char*)base + row * 128 + ((chunk ^ (row & 7)) << 4));
}

// ---------------- fused: LayerNorm1 (x,y) + weight prep + rpb4 table ----------------
// blocks [0, 21952): LN rows; blocks [21952, 26998): prep elements.
__global__ __launch_bounds__(256) void ln_prep_kernel(
    const float* __restrict__ in0, const float* __restrict__ in1,
    const float* __restrict__ g, const float* __restrict__ bb,
    ushortT* __restrict__ out0, ushortT* __restrict__ out1,
    const float* __restrict__ qkvw, const float* __restrict__ projw,
    const float* __restrict__ fc1w, const float* __restrict__ fc2w,
    const float* __restrict__ w1, const float* __restrict__ w2,
    const float* __restrict__ rpb,
    ushortT* qkvwb, ushortT* projwb, ushortT* fc1wb, ushortT* fc2wb,
    ushortT* w1rb, ushortT* w2rb, float4* rpb4) {
  int bid = blockIdx.x;
  if (bid < 21952) {
    int wave = threadIdx.x >> 6;
    int lane = threadIdx.x & 63;
    const float* in = (bid & 1) ? in1 : in0;
    ushortT* out = (bid & 1) ? out1 : out0;
    int row = (bid >> 1) * 4 + wave;
    const float* p = in + (size_t)row * CC;
    float v0 = p[lane], v1 = p[lane + 64], v2 = p[lane + 128];
    float s = v0 + v1 + v2;
    for (int o = 32; o; o >>= 1) s += __shfl_xor(s, o, 64);
    float mean = s * (1.0f / 192.0f);
    float d0 = v0 - mean, d1 = v1 - mean, d2 = v2 - mean;
    float qs = d0 * d0 + d1 * d1 + d2 * d2;
    for (int o = 32; o; o >>= 1) qs += __shfl_xor(qs, o, 64);
    float rs = rsqrtf(qs * (1.0f / 192.0f) + 1e-5f);
    ushortT* po = out + (size_t)row * CC;
    po[lane]       = f2b(d0 * rs * g[lane]       + bb[lane]);
    po[lane + 64]  = f2b(d1 * rs * g[lane + 64]  + bb[lane + 64]);
    po[lane + 128] = f2b(d2 * rs * g[lane + 128] + bb[lane + 128]);
    return;
  }
  int i = (bid - 21952) * 256 + threadIdx.x;
  if (i < 110592) { qkvwb[i] = f2b(qkvw[i]); return; }
  i -= 110592;
  if (i < 36864) { projwb[i] = f2b(projw[i]); return; }
  i -= 36864;
  if (i < 147456) { fc1wb[i] = f2b(fc1w[i]); return; }
  i -= 147456;
  if (i < 147456) { fc2wb[i] = f2b(fc2w[i]); return; }
  i -= 147456;
  if (i < 331776) {
    int o = i / 5184, r = i - o * 5184, tap = r / 192, c = r - tap * 192;
    w1rb[i] = f2b(w1[o * 5184 + c * 27 + tap]); return;
  }
  i -= 331776;
  if (i < 331776) {
    int o = i / 1728, r = i - o * 1728, tap = r / 64, c = r - tap * 64;
    w2rb[i] = f2b(w2[o * 1728 + c * 27 + tap]); return;
  }
  i -= 331776;
  if (i < 6 * 88 * 352) {
    int head = i / (88 * 352);
    int rem = i - head * 88 * 352;
    int qgrp = rem / 352, k = rem - qgrp * 352;
    float4 v = make_float4(0.f, 0.f, 0.f, 0.f);
    if (k < 343) {
      int b0 = k / 49, rb = k - b0 * 49; int b1 = rb / 7, b2 = rb - b1 * 7;
#pragma unroll
      for (int r = 0; r < 4; ++r) {
        int q = qgrp * 4 + r;
        if (q < 343) {
          int a0 = q / 49, ra = q - a0 * 49; int a1 = ra / 7, a2 = ra - a1 * 7;
          int ridx = ((a0 - b0 + 6) * 13 + (a1 - b1 + 6)) * 13 + (a2 - b2 + 6);
          (&v.x)[r] = rpb[ridx * 6 + head];
        }
      }
    }
    rpb4[i] = v;
  }
}

// ======== GEMM core: BM=64, BK=64, 4 waves (2x2), SINGLE buffer ========
#define CORE_IDS \
  const int tid = threadIdx.x; \
  const int wave = tid >> 6, lane = tid & 63; \
  const int fr = lane & 15, g = lane >> 4; \
  const int wr = wave >> 1, wc = wave & 1;

#define ZERO_ACC(NF) \
  f32x4 acc[2][NF]; \
  _Pragma("unroll") \
  for (int m_ = 0; m_ < 2; ++m_) { \
    _Pragma("unroll") \
    for (int n_ = 0; n_ < NF; ++n_) acc[m_][n_] = (f32x4){0.f, 0.f, 0.f, 0.f}; \
  }

#define SETUP_A_ROWMAJOR(BASE, LDA) \
  const ushortT* pa[2]; ushortT* la[2]; \
  _Pragma("unroll") \
  for (int i = 0; i < 2; ++i) { \
    int slot = i * 256 + tid; int row_ = slot >> 3; \
    int cc8 = ((slot & 7) ^ (row_ & 7)) * 8; \
    pa[i] = (BASE) + (size_t)(blockIdx.x * 64 + row_) * (LDA) + cc8; \
    la[i] = Asl + slot * 8; \
  }

#define SETUP_A_WINDOWED(BASE) \
  const ushortT* pa[2]; ushortT* la[2]; \
  _Pragma("unroll") \
  for (int i = 0; i < 2; ++i) { \
    int slot = i * 256 + tid; int row_ = slot >> 3; \
    int cc8 = ((slot & 7) ^ (row_ & 7)) * 8; \
    int bq_; int pos_ = tt_to_pos(blockIdx.x * 64 + row_, bq_); \
    pa[i] = (BASE) + ((size_t)bq_ * CL + pos_) * CC + cc8; \
    la[i] = Asl + slot * 8; \
  }

#define SETUP_B(BASE, ROWOFF, LDB, NR) \
  const ushortT* pb[NR]; ushortT* lb[NR]; \
  _Pragma("unroll") \
  for (int i = 0; i < NR; ++i) { \
    int slot = i * 256 + tid; int row_ = slot >> 3; \
    int cc8 = ((slot & 7) ^ (row_ & 7)) * 8; \
    pb[i] = (BASE) + (size_t)((ROWOFF) + row_) * (LDB) + cc8; \
    lb[i] = Bsl + slot * 8; \
  }

#define STAGE_AB(NR) \
  _Pragma("unroll") \
  for (int i = 0; i < 2; ++i) { stage16(pa[i], la[i]); pa[i] += 64; } \
  _Pragma("unroll") \
  for (int i = 0; i < NR; ++i) { stage16(pb[i], lb[i]); pb[i] += 64; }

#define CORE_MFMA(NF) \
  __syncthreads(); \
  _Pragma("unroll") \
  for (int kk = 0; kk < 2; ++kk) { \
    bf16x8 a0 = *ldsfrag(Asl, wr * 32 + fr, kk * 4 + g); \
    bf16x8 a1 = *ldsfrag(Asl, wr * 32 + 16 + fr, kk * 4 + g); \
    _Pragma("unroll") \
    for (int n_ = 0; n_ < NF; ++n_) { \
      bf16x8 bn = *ldsfrag(Bsl, wc * ((NF) * 16) + n_ * 16 + fr, kk * 4 + g); \
      acc[0][n_] = __builtin_amdgcn_mfma_f32_16x16x32_bf16(a0, bn, acc[0][n_], 0, 0, 0); \
      acc[1][n_] = __builtin_amdgcn_mfma_f32_16x16x32_bf16(a1, bn, acc[1][n_], 0, 0, 0); \
    } \
  } \
  __syncthreads();

// ======== 128x128 core, SINGLE buffer; M-block index from local var `mblk` ========
#define M128_ZERO \
  f32x4 acc[4][4]; \
  _Pragma("unroll") \
  for (int m_ = 0; m_ < 4; ++m_) \
    _Pragma("unroll") \
    for (int n_ = 0; n_ < 4; ++n_) acc[m_][n_] = (f32x4){0.f, 0.f, 0.f, 0.f};

#define M128_SETUP_A_ROWMAJOR(BASE, LDA) \
  const ushortT* pa[4]; ushortT* la[4]; \
  _Pragma("unroll") \
  for (int i = 0; i < 4; ++i) { \
    int slot = i * 256 + tid; int row_ = slot >> 3; \
    int cc8 = ((slot & 7) ^ (row_ & 7)) * 8; \
    pa[i] = (BASE) + (size_t)(mblk * 128 + row_) * (LDA) + cc8; \
    la[i] = Asl + slot * 8; \
  }

#define M128_SETUP_A_WINDOWED(BASE) \
  const ushortT* pa[4]; ushortT* la[4]; \
  _Pragma("unroll") \
  for (int i = 0; i < 4; ++i) { \
    int slot = i * 256 + tid; int row_ = slot >> 3; \
    int cc8 = ((slot & 7) ^ (row_ & 7)) * 8; \
    int bq_; int pos_ = tt_to_pos(mblk * 128 + row_, bq_); \
    pa[i] = (BASE) + ((size_t)bq_ * CL + pos_) * CC + cc8; \
    la[i] = Asl + slot * 8; \
  }

#define M128_SETUP_B(BASE, ROWOFF, LDB) \
  const ushortT* pb[4]; ushortT* lb[4]; \
  _Pragma("unroll") \
  for (int i = 0; i < 4; ++i) { \
    int slot = i * 256 + tid; int row_ = slot >> 3; \
    int cc8 = ((slot & 7) ^ (row_ & 7)) * 8; \
    pb[i] = (BASE) + (size_t)((ROWOFF) + row_) * (LDB) + cc8; \
    lb[i] = Bsl + slot * 8; \
  }

#define M128_STAGE \
  { _Pragma("unroll") \
    for (int i = 0; i < 4; ++i) { stage16(pa[i], la[i]); pa[i] += 64; } \
    _Pragma("unroll") \
    for (int i = 0; i < 4; ++i) { stage16(pb[i], lb[i]); pb[i] += 64; } }

#define M128_MFMA \
  { _Pragma("unroll") \
    for (int kk = 0; kk < 2; ++kk) { \
      bf16x8 am[4], bn[4]; \
      _Pragma("unroll") \
      for (int m_ = 0; m_ < 4; ++m_) am[m_] = *ldsfrag(Asl, wr * 64 + m_ * 16 + fr, kk * 4 + g); \
      _Pragma("unroll") \
      for (int n_ = 0; n_ < 4; ++n_) bn[n_] = *ldsfrag(Bsl, wc * 64 + n_ * 16 + fr, kk * 4 + g); \
      _Pragma("unroll") \
      for (int m_ = 0; m_ < 4; ++m_) \
        _Pragma("unroll") \
        for (int n_ = 0; n_ < 4; ++n_) \
          acc[m_][n_] = __builtin_amdgcn_mfma_f32_16x16x32_bf16(am[m_], bn[n_], acc[m_][n_], 0, 0, 0); \
    } }

#define M128_LOOP(KS) \
  _Pragma("unroll") \
  for (int ks = 0; ks < (KS); ++ks) { \
    M128_STAGE \
    __syncthreads(); \
    M128_MFMA \
    __syncthreads(); \
  }

// ---------------- Q projection -> bf16 [wh][n][32], scaled ----------------
__global__ __launch_bounds__(256) void gemm_q_n(const ushortT* __restrict__ xnb,
                                                const ushortT* __restrict__ qkvwb,
                                                const float* __restrict__ qkvb,
                                                ushortT* __restrict__ qout) {
  __shared__ alignas(16) ushortT Asl[64 * 64];
  __shared__ alignas(16) ushortT Bsl[192 * 64];
  CORE_IDS
  ZERO_ACC(6)
  SETUP_A_WINDOWED(xnb)
  SETUP_B(qkvwb, 0, 192, 6)
  for (int ks = 0; ks < 3; ++ks) {
    STAGE_AB(6)
    CORE_MFMA(6)
  }
#pragma unroll
  for (int n = 0; n < 6; ++n) {
    int jj = wc * 96 + n * 16 + fr;
    int head = jj >> 5, d = jj & 31;
    float bias = qkvb[jj];
#pragma unroll
    for (int m = 0; m < 2; ++m)
#pragma unroll
      for (int r = 0; r < 4; ++r) {
        int tt = blockIdx.x * 64 + wr * 32 + m * 16 + g * 4 + r;
        int bw = tt / 343, nn = tt - bw * 343;
        qout[(((size_t)bw * 6 + head) * 343 + nn) * 32 + d] =
            f2b((acc[m][n][r] + bias) * 0.17677669529663687f);
      }
  }
}

// ---------------- K,V projection (128x128 core, XCD-swizzled) ----------------
__global__ __launch_bounds__(256) void kv_128(const ushortT* __restrict__ ynb,
                                              const ushortT* __restrict__ qkvwb,
                                              const float* __restrict__ qkvb,
                                              ushortT* __restrict__ kout,
                                              ushortT* __restrict__ vout) {
  __shared__ alignas(16) ushortT Asl[8192];
  __shared__ alignas(16) ushortT Bsl[8192];
  CORE_IDS
  const int wid = xcd_swz(blockIdx.x, 343 * 3);
  const int mblk = wid / 3;
  const int jb = (wid - mblk * 3) * 128;
  M128_ZERO
  M128_SETUP_A_WINDOWED(ynb)
  M128_SETUP_B(qkvwb, 192 + jb, 192)
  M128_LOOP(3)
#pragma unroll
  for (int ni = 0; ni < 4; ++ni) {
    int jj = jb + wc * 64 + ni * 16 + fr;       // 0..383
    float bias = qkvb[192 + jj];
#pragma unroll
    for (int mi = 0; mi < 4; ++mi)
#pragma unroll
      for (int r = 0; r < 4; ++r) {
        int tt = mblk * 128 + wr * 64 + mi * 16 + g * 4 + r;
        int bw = tt / 343, nn = tt - bw * 343;
        float val = acc[mi][ni][r] + bias;
        if (jj < 192) {
          int head = jj >> 5, d = jj & 31;
          kout[(((size_t)bw * 6 + head) * 343 + nn) * 32 + d] = f2b(val);
        } else {
          int jv = jj - 192;
          int head = jv >> 5, d = jv & 31;
          vout[((size_t)bw * 6 + head) * 11264 + (size_t)d * 352 + nn] = f2b(val);
        }
      }
  }
}

// ---------------- conv core: BM=128, BN=64, single buffer, reg-prefetch A, XCD-swizzled ----------------
// MODE 2: split-K bf16 partial (conv1). MODE 0: N-split bf16+bias (conv2) + pooled sums.
template <int CIN, int COUTT, int MODE>
__global__ __launch_bounds__(256) void conv128(const ushortT* __restrict__ src,
                                               const ushortT* __restrict__ wrw,
                                               const float* __restrict__ bias,
                                               void* __restrict__ dst,
                                               float* __restrict__ part) {
  constexpr int KT = 27 * CIN;
  constexpr int KN = KT / 64;
  constexpr int NY = (MODE == 2) ? 4 : (COUTT / 64);
  constexpr int NBLK = 343 * NY;
  __shared__ alignas(16) ushortT Asl[8192];   // 16 KB
  __shared__ alignas(16) ushortT Bsl[4096];   // 8 KB
  const int tid = threadIdx.x;
  const int wave = tid >> 6, lane = tid & 63;
  const int fr = lane & 15, g = lane >> 4;
  const int wid = xcd_swz(blockIdx.x, NBLK);
  const int mblk = wid / NY;
  const int ysub = wid - mblk * NY;
  f32x4 acc[2][4];
#pragma unroll
  for (int m = 0; m < 2; ++m)
#pragma unroll
    for (int n = 0; n < 4; ++n) acc[m][n] = (f32x4){0.f, 0.f, 0.f, 0.f};

  const int kb = (MODE == 2) ? (ysub * KN) / 4 : 0;
  const int ke = (MODE == 2) ? ((ysub + 1) * KN) / 4 : KN;
  const int jbN = (MODE == 0) ? ysub * 64 : 0;

  const ushortT* srcb[4];
  ushortT* la[4];
  unsigned vmask[4];
#pragma unroll
  for (int i = 0; i < 4; ++i) {
    int slot = i * 256 + tid; int row_ = slot >> 3;
    int cc8 = ((slot & 7) ^ (row_ & 7)) * 8;
    int grow = mblk * 128 + row_;
    int bbq = grow / CL;
    int pos = grow - bbq * CL;
    int h = pos / 784, w = (pos / 28) % 28, t = pos % 28;
    unsigned vm = 0;
#pragma unroll
    for (int tap = 0; tap < 27; ++tap) {
      int dh = tap / 9 - 1, dw = (tap / 3) % 3 - 1, dt = tap % 3 - 1;
      bool ok = ((unsigned)(h + dh) < 28u) && ((unsigned)(w + dw) < 28u) &&
                ((unsigned)(t + dt) < 28u);
      vm |= (unsigned)ok << tap;
    }
    vmask[i] = vm;
    srcb[i] = src + ((size_t)bbq * CL + pos) * CIN + cc8;
    la[i] = Asl + slot * 8;
  }
  const ushortT* pb[2]; ushortT* lb[2];
#pragma unroll
  for (int i = 0; i < 2; ++i) {
    int slot = i * 256 + tid; int row_ = slot >> 3;
    int cc8 = ((slot & 7) ^ (row_ & 7)) * 8;
    pb[i] = wrw + (size_t)(jbN + row_) * KT + kb * 64 + cc8;
    lb[i] = Bsl + slot * 8;
  }

  auto loadA = [&](int ks, int i) -> uint4 {
    int tap, cb;
    if (CIN == 64) { tap = ks; cb = 0; }
    else           { tap = ks / 3; cb = (ks - tap * 3) * 64; }
    int off = ((tap / 9 - 1) * 784 + ((tap / 3) % 3 - 1) * 28 + (tap % 3 - 1)) * CIN + cb;
    uint4 v = make_uint4(0u, 0u, 0u, 0u);
    if ((vmask[i] >> tap) & 1u) v = *(const uint4*)(srcb[i] + off);
    return v;
  };

  uint4 vr[4];
#pragma unroll
  for (int i = 0; i < 4; ++i) vr[i] = loadA(kb, i);
  for (int ks = kb; ks < ke; ++ks) {
#pragma unroll
    for (int i = 0; i < 4; ++i) *(uint4*)la[i] = vr[i];
#pragma unroll
    for (int i = 0; i < 2; ++i) { stage16(pb[i], lb[i]); pb[i] += 64; }
    __syncthreads();
    bool more = (ks + 1 < ke);
    if (more) {
#pragma unroll
      for (int i = 0; i < 4; ++i) vr[i] = loadA(ks + 1, i);
    }
#pragma unroll
    for (int kk = 0; kk < 2; ++kk) {
      bf16x8 a0 = *ldsfrag(Asl, wave * 32 + fr, kk * 4 + g);
      bf16x8 a1 = *ldsfrag(Asl, wave * 32 + 16 + fr, kk * 4 + g);
#pragma unroll
      for (int n = 0; n < 4; ++n) {
        bf16x8 bn = *ldsfrag(Bsl, n * 16 + fr, kk * 4 + g);
        acc[0][n] = __builtin_amdgcn_mfma_f32_16x16x32_bf16(a0, bn, acc[0][n], 0, 0, 0);
        acc[1][n] = __builtin_amdgcn_mfma_f32_16x16x32_bf16(a1, bn, acc[1][n], 0, 0, 0);
      }
    }
    __syncthreads();
  }
  if (MODE == 2) {
    // bf16 partials (half the traffic of fp32; error ~1e-3 << threshold)
#pragma unroll
    for (int n = 0; n < 4; ++n) {
      int jj = n * 16 + fr;
#pragma unroll
      for (int m = 0; m < 2; ++m)
#pragma unroll
        for (int r = 0; r < 4; ++r) {
          int grow = mblk * 128 + wave * 32 + m * 16 + g * 4 + r;
          ((ushortT*)dst)[((size_t)ysub * CM + grow) * 64 + jj] = f2b(acc[m][n][r]);
        }
    }
  } else {
    // conv2 epilogue: bf16 store + fused spatial-pool partial sums
    float* red = (float*)Asl;   // 512 floats (Asl dead, post-barrier)
#pragma unroll
    for (int n = 0; n < 4; ++n) {
      int jj = n * 16 + fr;
      float bs = bias[jbN + jj];
      float s0 = 0.f, s1 = 0.f;
#pragma unroll
      for (int m = 0; m < 2; ++m)
#pragma unroll
        for (int r = 0; r < 4; ++r) {
          int grow = mblk * 128 + wave * 32 + m * 16 + g * 4 + r;
          float v = acc[m][n][r] + bs;
          ((ushortT*)dst)[(size_t)grow * COUTT + jbN + jj] = f2b(v);
          if (grow < CL) s0 += v; else s1 += v;
        }
      s0 += __shfl_xor(s0, 16, 64); s0 += __shfl_xor(s0, 32, 64);
      s1 += __shfl_xor(s1, 16, 64); s1 += __shfl_xor(s1, 32, 64);
      if (g == 0) {
        red[((wave * 4 + n) * 16 + fr) * 2 + 0] = s0;
        red[((wave * 4 + n) * 16 + fr) * 2 + 1] = s1;
      }
    }
    __syncthreads();
    if (tid < 128) {
      int chl = tid >> 1, bsel = tid & 1;       // chl in [0,64)
      float s = 0.f;
#pragma unroll
      for (int wv = 0; wv < 4; ++wv)
        s += red[((wv * 4 + (chl >> 4)) * 16 + (chl & 15)) * 2 + bsel];
      if (s != 0.0f) atomicAdd(&part[bsel * 192 + jbN + chl], s);
    }
  }
}

// ---------------- conv1 combine: 4 bf16 partials + bias -> GELU -> bf16 ----------------
__global__ __launch_bounds__(256) void comb1_kernel(const ushortT* __restrict__ pc,
                                                    const float* __restrict__ b1,
                                                    ushortT* __restrict__ h1b) {
  size_t idx = ((size_t)blockIdx.x * 256 + threadIdx.x) * 4;
  ushort4 a = *(const ushort4*)(pc + idx);
  ushort4 b = *(const ushort4*)(pc + (size_t)CM * 64 + idx);
  ushort4 c = *(const ushort4*)(pc + (size_t)CM * 128 + idx);
  ushort4 d = *(const ushort4*)(pc + (size_t)CM * 192 + idx);
  int c0 = (int)(idx & 63);
  ushortT o0 = f2b(gelu_exact(b2f(a.x) + b2f(b.x) + b2f(c.x) + b2f(d.x) + b1[c0 + 0]));
  ushortT o1 = f2b(gelu_exact(b2f(a.y) + b2f(b.y) + b2f(c.y) + b2f(d.y) + b1[c0 + 1]));
  ushortT o2 = f2b(gelu_exact(b2f(a.z) + b2f(b.z) + b2f(c.z) + b2f(d.z) + b1[c0 + 2]));
  ushortT o3 = f2b(gelu_exact(b2f(a.w) + b2f(b.w) + b2f(c.w) + b2f(d.w) + b1[c0 + 3]));
  unsigned int w0 = (unsigned int)o0 | ((unsigned int)o1 << 16);
  unsigned int w1 = (unsigned int)o2 | ((unsigned int)o3 << 16);
  *(uint2*)&h1b[idx] = make_uint2(w0, w1);
}

// ---------------- MFMA fused window attention (direct __shared__) + ca tail blocks ----------------
constexpr int KP  = 36;
constexpr int VP  = 356;
constexpr int VP2 = 200;

__global__ __launch_bounds__(256) void attn_ca(const ushortT* __restrict__ qb,
                                               const ushortT* __restrict__ kb,
                                               const ushortT* __restrict__ vb,
                                               const float* __restrict__ rpb4,
                                               ushortT* __restrict__ aout,
                                               const float* __restrict__ part,
                                               const float* __restrict__ ca1w,
                                               const float* __restrict__ ca1b,
                                               const float* __restrict__ ca2w,
                                               const float* __restrict__ ca2b,
                                               float* __restrict__ av) {
  __shared__ ushortT Kl[352 * KP];
  __shared__ ushortT Vt[32 * VP];
  __shared__ ushortT Pl[64 * VP2];
  const int tid = threadIdx.x;

  if (blockIdx.x >= 1536) {
    // channel-attention block (b = 0/1); uniform barriers, tid-guarded work
    int b = blockIdx.x - 1536;
    float* pl = (float*)Kl;
    float* hid = pl + 192;
    if (tid < 192) pl[tid] = part[b * 192 + tid] * (1.0f / (float)CL);
    __syncthreads();
    if (tid < 12) {
      float t = ca1b[tid];
      for (int i = 0; i < 192; ++i) t += ca1w[tid * 192 + i] * pl[i];
      hid[tid] = fmaxf(t, 0.0f);
    }
    __syncthreads();
    if (tid < 192) {
      float t = ca2b[tid];
#pragma unroll
      for (int j = 0; j < 12; ++j) t += ca2w[tid * 12 + j] * hid[j];
      av[b * 192 + tid] = 1.0f / (1.0f + __expf(-t));
    }
    return;
  }

  const int wave = tid >> 6, lane = tid & 63;
  const int fr = lane & 15, g = lane >> 4, fk = g * 8;
  const int wid = xcd_swz(blockIdx.x, 768 * 2);
  const int wh = wid >> 1;
  const int qhalf = wid & 1;
  const int bw = wh / 6, head = wh - bw * 6;
  const ushortT* kp = kb + (size_t)wh * 343 * 32;
  const ushortT* vp = vb + (size_t)wh * 11264;
  const ushortT* qp = qb + (size_t)wh * 343 * 32;
  const f32x4* bp4 = (const f32x4*)rpb4 + (size_t)head * 88 * 352;

  for (int c = tid; c < 1372; c += 256) {
    int key = c >> 2, part_ = c & 3;
    *(uint4*)&Kl[key * KP + part_ * 8] = *(const uint4*)(kp + (size_t)c * 8);
  }
  for (int c = tid; c < 1408; c += 256) {
    int d = c / 44, p = c - d * 44;
    *(uint4*)&Vt[d * VP + p * 8] = *(const uint4*)(vp + (size_t)c * 8);
  }
  __syncthreads();  // staging visible

  for (int qi = 0; qi < 3; ++qi) {
    const int q0 = (qhalf * 3 + qi) * 64;

    int qrow = q0 + wave * 16 + fr; if (qrow > 342) qrow = 342;
    bf16x8 aq = *(const bf16x8*)(qp + (size_t)qrow * 32 + fk);

    const int qgrp = (q0 + wave * 16) / 4 + g;
    f32x4 sc[22];
#pragma unroll
    for (int t = 0; t < 22; ++t) {
      f32x4 cini = bp4[(size_t)qgrp * 352 + t * 16 + fr];
      bf16x8 bk = *(const bf16x8*)&Kl[(t * 16 + fr) * KP + fk];
      sc[t] = __builtin_amdgcn_mfma_f32_16x16x32_bf16(aq, bk, cini, 0, 0, 0);
    }
    if (fr > 6) { sc[21][0] = -1e30f; sc[21][1] = -1e30f; sc[21][2] = -1e30f; sc[21][3] = -1e30f; }

    // softmax without max-subtract: |s| <= O(1), exp exact; pad exp(-1e30) -> 0
    float rinv[4];
#pragma unroll
    for (int r = 0; r < 4; ++r) {
      float sum = 0.0f;
#pragma unroll
      for (int t = 0; t < 22; ++t) {
        float e = __expf(sc[t][r]);
        sc[t][r] = e;
        sum += e;
      }
      sum += __shfl_xor(sum, 1, 64); sum += __shfl_xor(sum, 2, 64);
      sum += __shfl_xor(sum, 4, 64); sum += __shfl_xor(sum, 8, 64);
      rinv[r] = 1.0f / sum;
    }

    f32x4 o0 = {0.f, 0.f, 0.f, 0.f}, o1 = {0.f, 0.f, 0.f, 0.f};

#pragma unroll
    for (int t = 0; t < 12; ++t)
#pragma unroll
      for (int r = 0; r < 4; ++r)
        Pl[(wave * 16 + g * 4 + r) * VP2 + t * 16 + fr] = f2b(sc[t][r]);
    asm volatile("s_waitcnt lgkmcnt(0)" ::: "memory");
#pragma unroll
    for (int s = 0; s < 6; ++s) {
      bf16x8 ap  = *(const bf16x8*)&Pl[(wave * 16 + fr) * VP2 + s * 32 + fk];
      bf16x8 bv0 = *(const bf16x8*)&Vt[fr * VP + s * 32 + fk];
      bf16x8 bv1 = *(const bf16x8*)&Vt[(16 + fr) * VP + s * 32 + fk];
      o0 = __builtin_amdgcn_mfma_f32_16x16x32_bf16(ap, bv0, o0, 0, 0, 0);
      o1 = __builtin_amdgcn_mfma_f32_16x16x32_bf16(ap, bv1, o1, 0, 0, 0);
    }
    asm volatile("s_waitcnt lgkmcnt(0)" ::: "memory");

#pragma unroll
    for (int t = 12; t < 22; ++t)
#pragma unroll
      for (int r = 0; r < 4; ++r)
        Pl[(wave * 16 + g * 4 + r) * VP2 + (t - 12) * 16 + fr] = f2b(sc[t][r]);
    asm volatile("s_waitcnt lgkmcnt(0)" ::: "memory");
#pragma unroll
    for (int s = 0; s < 5; ++s) {
      bf16x8 ap  = *(const bf16x8*)&Pl[(wave * 16 + fr) * VP2 + s * 32 + fk];
      bf16x8 bv0 = *(const bf16x8*)&Vt[fr * VP + 192 + s * 32 + fk];
      bf16x8 bv1 = *(const bf16x8*)&Vt[(16 + fr) * VP + 192 + s * 32 + fk];
      o0 = __builtin_amdgcn_mfma_f32_16x16x32_bf16(ap, bv0, o0, 0, 0, 0);
      o1 = __builtin_amdgcn_mfma_f32_16x16x32_bf16(ap, bv1, o1, 0, 0, 0);
    }
    asm volatile("s_waitcnt lgkmcnt(0)" ::: "memory");

#pragma unroll
    for (int r = 0; r < 4; ++r) {
      int q = q0 + wave * 16 + g * 4 + r;
      if (q < 343) {
        float ri = rinv[r];
        size_t base = ((size_t)bw * 343 + q) * 192 + head * 32;
        aout[base + fr]      = f2b(o0[r] * ri);
        aout[base + 16 + fr] = f2b(o1[r] * ri);
      }
    }
  }
}

// ---------------- proj + window-reverse + residual + FUSED LayerNorm2 (bf16 xo) ----------------
__global__ __launch_bounds__(256) void proj_ln(const ushortT* __restrict__ attnrb,
                                               const ushortT* __restrict__ projwb,
                                               const float* __restrict__ projb,
                                               const float* __restrict__ x0,
                                               const ushortT* __restrict__ h2b,
                                               const float* __restrict__ cav,
                                               const float* __restrict__ n2g,
                                               const float* __restrict__ n2b,
                                               ushortT* __restrict__ xob,
                                               ushortT* __restrict__ hlnb) {
  __shared__ alignas(16) ushortT Asl[64 * 64];
  __shared__ alignas(16) ushortT Bsl[192 * 64];
  CORE_IDS
  ZERO_ACC(6)
  SETUP_A_ROWMAJOR(attnrb, CC)
  SETUP_B(projwb, 0, 192, 6)
  for (int ks = 0; ks < 3; ++ks) {
    STAGE_AB(6)
    CORE_MFMA(6)
  }
  // residual: acc <- x0 + acc + projb + h2*cav; write xob (bf16, spatial)
  size_t sbase[2][4];
#pragma unroll
  for (int m = 0; m < 2; ++m)
#pragma unroll
    for (int r = 0; r < 4; ++r) {
      int tt = blockIdx.x * 64 + wr * 32 + m * 16 + g * 4 + r;
      int bq_;
      int pos_ = tt_to_pos(tt, bq_);
      size_t base = ((size_t)bq_ * CL + pos_) * CC;
      sbase[m][r] = base;
#pragma unroll
      for (int n = 0; n < 6; ++n) {
        int jj = wc * 96 + n * 16 + fr;
        size_t addr = base + jj;
        float v = x0[addr] + acc[m][n][r] + projb[jj] + b2f(h2b[addr]) * cav[bq_ * 192 + jj];
        acc[m][n][r] = v;
        xob[addr] = f2b(v);
      }
    }
  // fused LN2: per-row stats via shfl + cross-wc LDS exchange
  float* stats = (float*)Asl;
#pragma unroll
  for (int m = 0; m < 2; ++m)
#pragma unroll
    for (int r = 0; r < 4; ++r) {
      float ps = 0.f, ps2 = 0.f;
#pragma unroll
      for (int n = 0; n < 6; ++n) { float v = acc[m][n][r]; ps += v; ps2 += v * v; }
      ps  += __shfl_xor(ps, 1, 64);  ps2 += __shfl_xor(ps2, 1, 64);
      ps  += __shfl_xor(ps, 2, 64);  ps2 += __shfl_xor(ps2, 2, 64);
      ps  += __shfl_xor(ps, 4, 64);  ps2 += __shfl_xor(ps2, 4, 64);
      ps  += __shfl_xor(ps, 8, 64);  ps2 += __shfl_xor(ps2, 8, 64);
      if (fr == 0) {
        int lrow = wr * 32 + m * 16 + g * 4 + r;
        stats[lrow * 4 + wc * 2]     = ps;
        stats[lrow * 4 + wc * 2 + 1] = ps2;
      }
    }
  __syncthreads();
#pragma unroll
  for (int m = 0; m < 2; ++m)
#pragma unroll
    for (int r = 0; r < 4; ++r) {
      int lrow = wr * 32 + m * 16 + g * 4 + r;
      float s  = stats[lrow * 4]     + stats[lrow * 4 + 2];
      float s2 = stats[lrow * 4 + 1] + stats[lrow * 4 + 3];
      float mean = s * (1.0f / 192.0f);
      float var  = s2 * (1.0f / 192.0f) - mean * mean;
      float rs = rsqrtf(var + 1e-5f);
      ushortT* po = hlnb + sbase[m][r];   // spatial row
#pragma unroll
      for (int n = 0; n < 6; ++n) {
        int jj = wc * 96 + n * 16 + fr;
        po[jj] = f2b((acc[m][n][r] - mean) * rs * n2g[jj] + n2b[jj]);
      }
    }
}

// ---------------- MLP fc1 (128x128 core, XCD-swizzled) ----------------
__global__ __launch_bounds__(256) void fc1_128(const ushortT* __restrict__ hlnb,
                                               const ushortT* __restrict__ fc1wb,
                                               const float* __restrict__ fc1b,
                                               ushortT* __restrict__ hidb) {
  __shared__ alignas(16) ushortT Asl[8192];
  __shared__ alignas(16) ushortT Bsl[8192];
  CORE_IDS
  const int wid = xcd_swz(blockIdx.x, 343 * 6);
  const int mblk = wid / 6;
  const int jb = (wid - mblk * 6) * 128;
  M128_ZERO
  M128_SETUP_A_ROWMAJOR(hlnb, CC)
  M128_SETUP_B(fc1wb, jb, 192)
  M128_LOOP(3)
#pragma unroll
  for (int ni = 0; ni < 4; ++ni) {
    int jj = jb + wc * 64 + ni * 16 + fr;
    float bs = fc1b[jj];
#pragma unroll
    for (int mi = 0; mi < 4; ++mi)
#pragma unroll
      for (int r = 0; r < 4; ++r) {
        int grow = mblk * 128 + wr * 64 + mi * 16 + g * 4 + r;
        hidb[(size_t)grow * 768 + jj] = f2b(gelu_exact(acc[mi][ni][r] + bs));
      }
  }
}

// ---------------- MLP fc2 + final residual (bf16 xo) -> d_out ----------------
__global__ __launch_bounds__(256) void fc2_n(const ushortT* __restrict__ hidb,
                                             const ushortT* __restrict__ fc2wb,
                                             const float* __restrict__ fc2b,
                                             const ushortT* __restrict__ xob,
                                             float* __restrict__ out) {
  __shared__ alignas(16) ushortT Asl[64 * 64];
  __shared__ alignas(16) ushortT Bsl[192 * 64];
  CORE_IDS
  ZERO_ACC(6)
  SETUP_A_ROWMAJOR(hidb, 768)
  SETUP_B(fc2wb, 0, 768, 6)
  for (int ks = 0; ks < 12; ++ks) {
    STAGE_AB(6)
    CORE_MFMA(6)
  }
#pragma unroll
  for (int n = 0; n < 6; ++n) {
    int jj = wc * 96 + n * 16 + fr;
    float bs = fc2b[jj];
#pragma unroll
    for (int m = 0; m < 2; ++m)
#pragma unroll
      for (int r = 0; r < 4; ++r) {
        int grow = blockIdx.x * 64 + wr * 32 + m * 16 + g * 4 + r;
        size_t addr = (size_t)grow * CC + jj;
        out[addr] = b2f(xob[addr]) + acc[m][n][r] + bs;
      }
  }
}

// ---------------- launch ----------------
extern "C" void kernel_launch(void* const* d_in, const int* in_sizes, int n_in,
                              void* d_out, int out_size, void* d_ws, size_t ws_size,
                              hipStream_t stream) {
  const float* x     = (const float*)d_in[0];
  const float* y     = (const float*)d_in[1];
  const float* n1g   = (const float*)d_in[3];
  const float* n1b   = (const float*)d_in[4];
  const float* qkvw  = (const float*)d_in[5];
  const float* qkvb  = (const float*)d_in[6];
  const float* projw = (const float*)d_in[7];
  const float* projb = (const float*)d_in[8];
  const float* rpb   = (const float*)d_in[9];
  const float* n2g   = (const float*)d_in[10];
  const float* n2b   = (const float*)d_in[11];
  const float* fc1w  = (const float*)d_in[12];
  const float* fc1b  = (const float*)d_in[13];
  const float* fc2w  = (const float*)d_in[14];
  const float* fc2b  = (const float*)d_in[15];
  const float* w1    = (const float*)d_in[16];
  const float* b1    = (const float*)d_in[17];
  const float* w2    = (const float*)d_in[18];
  const float* b2    = (const float*)d_in[19];
  const float* ca1w  = (const float*)d_in[20];
  const float* ca1b  = (const float*)d_in[21];
  const float* ca2w  = (const float*)d_in[22];
  const float* ca2b  = (const float*)d_in[23];

  char* W = (char*)d_ws;
  float* out = (float*)d_out;

  ushortT* xnb  = (ushortT*)(W + 0);
  ushortT* ynb  = (ushortT*)(W + 16859136);
  ushortT* qbb  = (ushortT*)(W + 33718272);
  ushortT* kbb  = (ushortT*)(W + 50577408);
  ushortT* vbb  = (ushortT*)(W + 67436544);   // [wh][32][352] bf16
  ushortT* h1b  = (ushortT*)(W + 84738048);
  ushortT* h2b  = (ushortT*)(W + 90357760);   // bf16 (16.9 MB)
  ushortT* xob  = (ushortT*)(W + 124076032);  // bf16 residual stream (16.9 MB)
  char*    SM   = W + 157794304;
  ushortT* qkvwb  = (ushortT*)(SM);
  ushortT* projwb = (ushortT*)(SM + 221184);
  ushortT* fc1wb  = (ushortT*)(SM + 294912);
  ushortT* fc2wb  = (ushortT*)(SM + 589824);
  ushortT* w1rb   = (ushortT*)(SM + 884736);
  ushortT* w2rb   = (ushortT*)(SM + 1548288);
  float*   rpb4   = (float*)(SM + 2211840);   // 2,973,696 B
  float*   av     = (float*)(SM + 5185536);   // 384 floats
  float*   part   = (float*)(SM + 5187072);   // 384 floats (pooled sums)
  ushortT* pc1    = (ushortT*)(SM + 5319168); // 4*CM*64 bf16 = 22,478,848 B
  ushortT* attnrb = xnb;
  ushortT* hlnb   = ynb;
  ushortT* hidb   = (ushortT*)(W + 33718272);

  // 0. zero pooled-sum accumulator (graph-capturable)
  hipMemsetAsync(part, 0, 2 * 192 * sizeof(float), stream);

  // 1. fused LN1(x,y) + weight prep + rpb4 table
  ln_prep_kernel<<<21952 + 5046, 256, 0, stream>>>(
      x, y, n1g, n1b, xnb, ynb,
      qkvw, projw, fc1w, fc2w, w1, w2, rpb,
      qkvwb, projwb, fc1wb, fc2wb, w1rb, w2rb, (float4*)rpb4);

  // 2. QKV projections
  gemm_q_n<<<686, 256, 0, stream>>>(xnb, qkvwb, qkvb, qbb);
  kv_128<<<343 * 3, 256, 0, stream>>>(ynb, qkvwb, qkvb, kbb, vbb);

  // 3. CAB convs: conv1 K-split 4 (bf16 partials) -> combine -> conv2 (bf16 + fused pool)
  conv128<192, 64, 2><<<343 * 4, 256, 0, stream>>>(xnb, w1rb, b1, pc1, nullptr);
  comb1_kernel<<<2744, 256, 0, stream>>>(pc1, b1, h1b);
  conv128<64, 192, 0><<<343 * 3, 256, 0, stream>>>(h1b, w2rb, b2, h2b, part);

  // 4. attention (+ channel-attention tail blocks) -> bf16 (aliases xnb)
  attn_ca<<<1538, 256, 0, stream>>>(qbb, kbb, vbb, rpb4, attnrb,
                                    part, ca1w, ca1b, ca2w, ca2b, av);

  // 5. proj + window reverse + residual + fused LN2 (writes bf16 xob and hlnb)
  proj_ln<<<686, 256, 0, stream>>>(attnrb, projwb, projb, x, h2b, av, n2g, n2b, xob, hlnb);

  // 6. MLP
  fc1_128<<<343 * 6, 256, 0, stream>>>(hlnb, fc1wb, fc1b, hidb);
  fc2_n<<<686, 256, 0, stream>>>(hidb, fc2wb, fc2b, xob, out);
}